// Round 7
// baseline (6225.762 us; speedup 1.0000x reference)
//
#include <hip/hip_runtime.h>

#define NB 8
#define NP 4096
#define NS 1024
#define PROGSTRIDE 32   // one 128B cache line per cloud's progress word
#define SELB 32         // select blocks
#define MLP1B 72        // seg1 mlp blocks
#define MLP2B 144       // seg2 mlp blocks

typedef _Float16 f16x8 __attribute__((ext_vector_type(8)));
typedef _Float16 f16x4 __attribute__((ext_vector_type(4)));
typedef float f32x4 __attribute__((ext_vector_type(4)));

// DPP-fused max step: v = max(v, dpp_move(v, ctrl)). bound_ctrl=false keeps
// old value on invalid lanes -> max(v,v)=v, harmless.
#define DPP_MAX(v, ctrl)                                                     \
    v = fmaxf(v, __int_as_float(__builtin_amdgcn_update_dpp(                 \
                __float_as_int(v), __float_as_int(v), (ctrl), 0xf, 0xf, false)))

struct PrepArgs {
    const float* src[9];
    _Float16* dst[9];
    int kr[9], kp[9], nc[9];
};

struct MlpW {
    const _Float16* w[9];
    const float* bias[9];
};

// ========================= Selection body ==========================
// ROUND-7 kernel (measured win). Early-exit binary search on uint(d2) bits,
// no LDS staging, one center per wave. Bit-identical to exact top-k.
template <int K>
__device__ __forceinline__ void select_center(
        const float* __restrict__ pb,
        const float* __restrict__ centers,
        int* __restrict__ nbr, int* __restrict__ nvalid,
        float r2, int scid) {
#pragma clang fp contract(off)
    const int lane = threadIdx.x & 63;
    const unsigned kr2 = __float_as_uint(r2);
    const float cx = centers[scid * 3 + 0];
    const float cy = centers[scid * 3 + 1];
    const float cz = centers[scid * 3 + 2];

    unsigned key[64];
#pragma unroll
    for (int i = 0; i < 64; ++i) {
        const float* pp = pb + (size_t)(lane + i * 64) * 3;
        float dx = pp[0] - cx; float sx = dx * dx;
        float dy = pp[1] - cy; float sy = dy * dy;
        float dz = pp[2] - cz; float sz = dz * dz;
        float d2 = sx + sy; d2 = d2 + sz;
        key[i] = __float_as_uint(d2);
    }

    const unsigned long long below = (1ull << lane) - 1ull;
    int c_cnt = 0;
#pragma unroll
    for (int i = 0; i < 64; ++i)
        c_cnt += __popcll(__ballot(key[i] <= kr2));

    unsigned thr = kr2;
    int nv = c_cnt;
    bool need_ties = false;
    unsigned tkey = 0;
    if (c_cnt > K) {
        nv = K;
        unsigned lo = 0, hi = kr2;
        need_ties = true;
        while (lo < hi) {
            unsigned mid = lo + ((hi - lo) >> 1);
            int cnt = 0;
#pragma unroll
            for (int i = 0; i < 64; ++i)
                cnt += __popcll(__ballot(key[i] <= mid));
            if (cnt == K) { thr = mid; need_ties = false; break; }
            if (cnt > K) hi = mid; else lo = mid + 1;
        }
        tkey = lo;
    }

    if (!need_ties) {
        int base = 0;
#pragma unroll
        for (int i = 0; i < 64; ++i) {
            unsigned long long m = __ballot(key[i] <= thr);
            if (key[i] <= thr)
                nbr[(size_t)scid * K + base + __popcll(m & below)] = lane + i * 64;
            base += __popcll(m);
        }
    } else {
        const unsigned t = tkey;
        int m_cnt = 0;
#pragma unroll
        for (int i = 0; i < 64; ++i)
            m_cnt += __popcll(__ballot(key[i] < t));
        const int rem = K - m_cnt;
        int base = 0, tcnt = 0;
#pragma unroll
        for (int i = 0; i < 64; ++i) {
            unsigned long long lt = __ballot(key[i] < t);
            unsigned long long eq = __ballot(key[i] == t);
            if (key[i] < t) {
                nbr[(size_t)scid * K + base + __popcll(lt & below)] = lane + i * 64;
            } else if (key[i] == t) {
                int tr = tcnt + __popcll(eq & below);
                if (tr < rem) nbr[(size_t)scid * K + (m_cnt + tr)] = lane + i * 64;
            }
            base += __popcll(lt);
            tcnt += __popcll(eq);
        }
    }
    if (lane == 0) nvalid[scid] = nv;
}

// ====================== 8-wave MLP body (512 threads) ======================
// Same math as the 4-wave mlp_body, N split 8 ways (needs C % 128 == 0, so
// seg1/seg2 only). Per-unit readiness: spin until ready[u]==8 (one release
// add per completed select task). Barrier count per unit is fixed ->
// per-block barrier safety regardless of per-block unit counts.
template <int M, int C1, int C2, int C3, int OFF>
__device__ void mlp8_body(
        char* smem,
        const float* __restrict__ x, const float* __restrict__ pos,
        const float* __restrict__ centers,
        const int* __restrict__ nbr, const int* __restrict__ nvalid,
        const _Float16* __restrict__ wt1, const _Float16* __restrict__ wt2,
        const _Float16* __restrict__ wt3,
        const float* __restrict__ b1, const float* __restrict__ b2,
        const float* __restrict__ b3,
        float* __restrict__ out,
        int* __restrict__ ready, int ublk, int ustride) {
    constexpr int K1P = 96;
    constexpr int S1 = K1P + 8;
    constexpr int S2 = C1 + 8;
    constexpr int S3 = C2 + 8;
    constexpr int MT = M / 16;
    constexpr int NCH1 = C1 / 8, NCH2 = C2 / 8, NCH3 = C3 / 8;
    constexpr int NT1 = NCH1 / 16, NT2 = NCH2 / 16, NT3 = NCH3 / 16;
    constexpr int KT1 = K1P / 32, KT2 = C1 / 32, KT3 = C2 / 32;

    _Float16* feat = (_Float16*)smem;
    _Float16* h1 = feat + M * S1;
    _Float16* h2 = h1 + M * S2;
    int* outmax = (int*)(h2 + M * S3);

    const int tid = threadIdx.x;
    const int lane = tid & 63;
    const int w = tid >> 6;          // 0..7
    const int lm = lane & 15;
    const int lq = lane >> 4;

    f16x8 wf1[NT1][KT1], wf2[NT2][KT2], wf3[NT3][KT3];
    float bb1[NT1], bb2[NT2], bb3[NT3];
#pragma unroll
    for (int nt = 0; nt < NT1; ++nt) {
        int n = w * NCH1 + nt * 16 + lm;
        bb1[nt] = b1[n];
#pragma unroll
        for (int kt = 0; kt < KT1; ++kt)
            wf1[nt][kt] = *(const f16x8*)(wt1 + (size_t)n * K1P + kt * 32 + lq * 8);
    }
#pragma unroll
    for (int nt = 0; nt < NT2; ++nt) {
        int n = w * NCH2 + nt * 16 + lm;
        bb2[nt] = b2[n];
#pragma unroll
        for (int kt = 0; kt < KT2; ++kt)
            wf2[nt][kt] = *(const f16x8*)(wt2 + (size_t)n * C1 + kt * 32 + lq * 8);
    }
#pragma unroll
    for (int nt = 0; nt < NT3; ++nt) {
        int n = w * NCH3 + nt * 16 + lm;
        bb3[nt] = b3[n];
#pragma unroll
        for (int kt = 0; kt < KT3; ++kt)
            wf3[nt][kt] = *(const f16x8*)(wt3 + (size_t)n * C2 + kt * 32 + lq * 8);
    }

    for (int u = ublk; u < 1024; u += ustride) {
        // wait until all 8 centers of this unit are selected
        while (__hip_atomic_load(&ready[u], __ATOMIC_ACQUIRE,
                                 __HIP_MEMORY_SCOPE_AGENT) < 8)
            __builtin_amdgcn_s_sleep(32);
        for (int cc = 0; cc < 8; ++cc) {
            const int cid = u * 8 + cc;
            const int bidx = cid >> 10;
            const int nv = nvalid[cid];
            const float cx = centers[cid * 3 + 0];
            const float cy = centers[cid * 3 + 1];
            const float cz = centers[cid * 3 + 2];
            for (int i = tid; i < C3; i += 512) outmax[i] = 0;

            // gather A: x features (stale rows masked later)
#pragma unroll
            for (int it = tid; it < M * 16; it += 512) {
                const int r = it >> 4, sub = it & 15;
                if (r < nv) {
                    int pt = nbr[(size_t)cid * M + r];
                    float4 v = *(const float4*)(x + ((size_t)(bidx * NP) + pt) * 64 + sub * 4);
                    f16x4 hv = {(_Float16)v.x, (_Float16)v.y, (_Float16)v.z, (_Float16)v.w};
                    *(f16x4*)(feat + r * S1 + sub * 4) = hv;
                }
            }
            // gather B: pos-rel + zero K-pad
#pragma unroll
            for (int it = tid; it < M * 4; it += 512) {
                const int r = it >> 2, q = it & 3;
                f16x8 z = {(_Float16)0.f, (_Float16)0.f, (_Float16)0.f, (_Float16)0.f,
                           (_Float16)0.f, (_Float16)0.f, (_Float16)0.f, (_Float16)0.f};
                if (q == 0 && r < nv) {
                    int pt = nbr[(size_t)cid * M + r];
                    const float* pr = pos + ((size_t)(bidx * NP) + pt) * 3;
                    z[0] = (_Float16)(pr[0] - cx);
                    z[1] = (_Float16)(pr[1] - cy);
                    z[2] = (_Float16)(pr[2] - cz);
                }
                *(f16x8*)(feat + r * S1 + 64 + q * 8) = z;
            }
            __syncthreads();

            // layer 1
#pragma unroll
            for (int mt = 0; mt < MT; ++mt) {
                f16x8 a[KT1];
#pragma unroll
                for (int kt = 0; kt < KT1; ++kt)
                    a[kt] = *(const f16x8*)(feat + (mt * 16 + lm) * S1 + kt * 32 + lq * 8);
#pragma unroll
                for (int nt = 0; nt < NT1; ++nt) {
                    f32x4 acc = {bb1[nt], bb1[nt], bb1[nt], bb1[nt]};
#pragma unroll
                    for (int kt = 0; kt < KT1; ++kt)
                        acc = __builtin_amdgcn_mfma_f32_16x16x32_f16(a[kt], wf1[nt][kt], acc, 0, 0, 0);
                    const int gc = w * NCH1 + nt * 16 + lm;
#pragma unroll
                    for (int rg = 0; rg < 4; ++rg)
                        h1[(mt * 16 + lq * 4 + rg) * S2 + gc] = (_Float16)fmaxf(acc[rg], 0.f);
                }
            }
            __syncthreads();

            // layer 2
#pragma unroll
            for (int mt = 0; mt < MT; ++mt) {
                f16x8 a[KT2];
#pragma unroll
                for (int kt = 0; kt < KT2; ++kt)
                    a[kt] = *(const f16x8*)(h1 + (mt * 16 + lm) * S2 + kt * 32 + lq * 8);
#pragma unroll
                for (int nt = 0; nt < NT2; ++nt) {
                    f32x4 acc = {bb2[nt], bb2[nt], bb2[nt], bb2[nt]};
#pragma unroll
                    for (int kt = 0; kt < KT2; ++kt)
                        acc = __builtin_amdgcn_mfma_f32_16x16x32_f16(a[kt], wf2[nt][kt], acc, 0, 0, 0);
                    const int gc = w * NCH2 + nt * 16 + lm;
#pragma unroll
                    for (int rg = 0; rg < 4; ++rg)
                        h2[(mt * 16 + lq * 4 + rg) * S3 + gc] = (_Float16)fmaxf(acc[rg], 0.f);
                }
            }
            __syncthreads();

            // layer 3 + masked max
#pragma unroll
            for (int mt = 0; mt < MT; ++mt) {
                f16x8 a[KT3];
#pragma unroll
                for (int kt = 0; kt < KT3; ++kt)
                    a[kt] = *(const f16x8*)(h2 + (mt * 16 + lm) * S3 + kt * 32 + lq * 8);
#pragma unroll
                for (int nt = 0; nt < NT3; ++nt) {
                    f32x4 acc = {bb3[nt], bb3[nt], bb3[nt], bb3[nt]};
#pragma unroll
                    for (int kt = 0; kt < KT3; ++kt)
                        acc = __builtin_amdgcn_mfma_f32_16x16x32_f16(a[kt], wf3[nt][kt], acc, 0, 0, 0);
                    float mx = -1.f;
#pragma unroll
                    for (int rg = 0; rg < 4; ++rg) {
                        int row = mt * 16 + lq * 4 + rg;
                        float v = fmaxf(acc[rg], 0.f);
                        if (row < nv) mx = fmaxf(mx, v);
                    }
                    mx = fmaxf(mx, __shfl_xor(mx, 16));
                    mx = fmaxf(mx, __shfl_xor(mx, 32));
                    if (lane < 16)
                        atomicMax(&outmax[w * NCH3 + nt * 16 + lm], __float_as_int(mx));
                }
            }
            __syncthreads();
            for (int i = tid; i < C3; i += 512)
                out[(size_t)cid * 640 + OFF + i] = __int_as_float(outmax[i]);
            __syncthreads();
        }
    }
}

// ============ UBER KERNEL: fps -> select -> mlp(seg1,seg2) pipeline ==========
// ROUND-11. Roles by blockIdx: [0,8) fps producers (R6-identical); [8,40)
// select workers (256 waves; 2.4x headroom over fps's 31 tasks/us);
// [40,112) seg1 mlp; [112,256) seg2 mlp (8-wave blocks, per-unit ready
// counters; seg0 mlp stays in a trailing kernel since C1=64 doesn't split
// 8 ways). mlp blocks redundantly prep ALL weight matrices in-preamble
// (idempotent same-value writes -> no cross-block sync needed).
// SAFETY: 256 blocks, 1/CU, all resident; waiters never starve producers.
// prog+ready zeroed via hipMemsetAsync each launch (graph-replay safe).
__global__ __launch_bounds__(512, 1) void fps_select_mlp(
        const float* __restrict__ pos,
        float* __restrict__ centers,
        float* __restrict__ out_pos,
        float* __restrict__ out_batch,
        int* __restrict__ nbr0, int* __restrict__ nbr1, int* __restrict__ nbr2,
        int* __restrict__ nval,
        unsigned* __restrict__ prog,
        int* __restrict__ ready,          // [2][1024]
        const float* __restrict__ x,
        float* __restrict__ out,
        PrepArgs pa, MlpW ww) {
#pragma clang fp contract(off)
    extern __shared__ char smem[];
    const int tid = threadIdx.x;
    const int lane = tid & 63;
    const int blk = blockIdx.x;

    if (blk < NB) {
        // ------------------------ producer: FPS (R6-identical) --------------
        const int b = blk;
        const int wid = tid >> 6;
        __shared__ float4 slot[2][8];

        const float* pb = pos + (size_t)b * NP * 3;
        float px[8], py[8], pz[8], md[8];
        {
            const float4* pv = (const float4*)(pb + tid * 24);
            float4 q0 = pv[0], q1 = pv[1], q2 = pv[2];
            float4 q3 = pv[3], q4 = pv[4], q5 = pv[5];
            px[0] = q0.x; py[0] = q0.y; pz[0] = q0.z;
            px[1] = q0.w; py[1] = q1.x; pz[1] = q1.y;
            px[2] = q1.z; py[2] = q1.w; pz[2] = q2.x;
            px[3] = q2.y; py[3] = q2.z; pz[3] = q2.w;
            px[4] = q3.x; py[4] = q3.y; pz[4] = q3.z;
            px[5] = q3.w; py[5] = q4.x; pz[5] = q4.y;
            px[6] = q4.z; py[6] = q4.w; pz[6] = q5.x;
            px[7] = q5.y; py[7] = q5.z; pz[7] = q5.w;
        }
#pragma unroll
        for (int j = 0; j < 8; ++j) md[j] = __builtin_inff();
        for (int t = tid; t < NS; t += 512) out_batch[b * NS + t] = (float)b;

        float cx = pb[0], cy = pb[1], cz = pb[2];
        if (tid == 0) {
            size_t o = (size_t)(b * NS) * 3;
            centers[o + 0] = cx; centers[o + 1] = cy; centers[o + 2] = cz;
            out_pos[o + 0] = cx; out_pos[o + 1] = cy; out_pos[o + 2] = cz;
        }

        int par = 0;
        for (int t = 1; t < NS; ++t) {
            float bv = -1.0f, bx = cx, by = cy, bz = cz;
#pragma unroll
            for (int j = 0; j < 8; ++j) {
                float dx = px[j] - cx; float sx = dx * dx;
                float dy = py[j] - cy; float sy = dy * dy;
                float dz = pz[j] - cz; float sz = dz * dz;
                float d = sx + sy; d = d + sz;
                float m = fminf(md[j], d);
                md[j] = m;
                bool c = m > bv;
                bv = c ? m : bv;
                bx = c ? px[j] : bx;
                by = c ? py[j] : by;
                bz = c ? pz[j] : bz;
            }
            float v = bv;
            DPP_MAX(v, 0x111);
            DPP_MAX(v, 0x112);
            DPP_MAX(v, 0x114);
            DPP_MAX(v, 0x118);
            DPP_MAX(v, 0x142);
            DPP_MAX(v, 0x143);
            const float mx = __int_as_float(
                __builtin_amdgcn_readlane(__float_as_int(v), 63));
            unsigned long long tie = __ballot(bv == mx);
            if (lane == __ffsll(tie) - 1)
                slot[par][wid] = make_float4(mx, bx, by, bz);
            __syncthreads();
            float4 s0 = slot[par][0], s1 = slot[par][1];
            float4 s2 = slot[par][2], s3 = slot[par][3];
            float4 s4 = slot[par][4], s5 = slot[par][5];
            float4 s6 = slot[par][6], s7 = slot[par][7];
            float4 a01 = (s1.x > s0.x) ? s1 : s0;
            float4 a23 = (s3.x > s2.x) ? s3 : s2;
            float4 a45 = (s5.x > s4.x) ? s5 : s4;
            float4 a67 = (s7.x > s6.x) ? s7 : s6;
            float4 b03 = (a23.x > a01.x) ? a23 : a01;
            float4 b47 = (a67.x > a45.x) ? a67 : a45;
            float4 wn = (b47.x > b03.x) ? b47 : b03;
            cx = wn.y; cy = wn.z; cz = wn.w;
            if (tid == 0) {
                size_t o = (size_t)(b * NS + t) * 3;
                centers[o + 0] = cx; centers[o + 1] = cy; centers[o + 2] = cz;
                out_pos[o + 0] = cx; out_pos[o + 1] = cy; out_pos[o + 2] = cz;
                if ((t & 15) == 15)
                    __hip_atomic_store(&prog[b * PROGSTRIDE], (unsigned)(t + 1),
                                       __ATOMIC_RELEASE, __HIP_MEMORY_SCOPE_AGENT);
            }
            par ^= 1;
        }
    } else if (blk < NB + SELB) {
        // ------------------------ select workers ----------------------------
        const int wblk = blk - NB;               // 0..31
        const int wid = tid >> 6;                // 0..7
        const int wave_id = wblk * 8 + wid;      // 0..255
        const int NWAVE = SELB * 8;              // 256
        const int NTASK = 3 * NB * NS;           // 24576
        for (int T = wave_id; T < NTASK; T += NWAVE) {
            const int s = T / 24;
            const int r = T - s * 24;
            const int b = r & 7;
            const int seg = r >> 3;
            const int scid = b * NS + s;
            while (__hip_atomic_load(&prog[b * PROGSTRIDE], __ATOMIC_ACQUIRE,
                                     __HIP_MEMORY_SCOPE_AGENT) <= (unsigned)s)
                __builtin_amdgcn_s_sleep(32);
            const float* pb = pos + (size_t)b * NP * 3;
            if (seg == 0)
                select_center<16>(pb, centers, nbr0, nval,
                                  (float)(0.1 * 0.1), scid);
            else if (seg == 1)
                select_center<32>(pb, centers, nbr1, nval + 8192,
                                  (float)(0.2 * 0.2), scid);
            else
                select_center<64>(pb, centers, nbr2, nval + 16384,
                                  (float)(0.4 * 0.4), scid);
            if (seg >= 1) {
                // drain this wave's nbr/nval stores, then signal the unit
                asm volatile("s_waitcnt vmcnt(0)" ::: "memory");
                if (lane == 0)
                    __hip_atomic_fetch_add(&ready[(seg - 1) * 1024 + (scid >> 3)], 1,
                                           __ATOMIC_RELEASE, __HIP_MEMORY_SCOPE_AGENT);
            }
        }
    } else {
        // ------------------------ mlp workers (seg1 / seg2) -----------------
        // redundant idempotent weight prep (each block writes all it reads)
        {
#pragma unroll 1
            for (int m = 0; m < 9; ++m) {
                const int kp = pa.kp[m], kr = pa.kr[m], nc = pa.nc[m];
                const float* src = pa.src[m];
                _Float16* dst = pa.dst[m];
                const int tot = kp * nc;
                for (int i = tid; i < tot; i += 512) {
                    int n = i / kp, k = i - n * kp;
                    dst[i] = (k < kr) ? (_Float16)src[(size_t)k * nc + n]
                                      : (_Float16)0.f;
                }
            }
            __syncthreads();   // drains vmcnt -> own stores visible via L2
        }
        if (blk < NB + SELB + MLP1B) {
            mlp8_body<32, 128, 128, 256, 128>(smem, x, pos, centers,
                nbr1, nval + 8192,
                ww.w[3], ww.w[4], ww.w[5], ww.bias[3], ww.bias[4], ww.bias[5],
                out, ready, blk - (NB + SELB), MLP1B);
        } else {
            mlp8_body<64, 128, 128, 256, 384>(smem, x, pos, centers,
                nbr2, nval + 16384,
                ww.w[6], ww.w[7], ww.w[8], ww.bias[6], ww.bias[7], ww.bias[8],
                out, ready + 1024, blk - (NB + SELB + MLP1B), MLP2B);
        }
    }
}

// ================== 4-wave MLP body (seg0 trailing kernel) ==================
template <int M, int C1, int C2, int C3, int OFF, int NCTR>
__device__ void mlp_body(
        char* smem,
        const float* __restrict__ x, const float* __restrict__ pos,
        const float* __restrict__ centers,
        const int* __restrict__ nbr, const int* __restrict__ nvalid,
        const _Float16* __restrict__ wt1, const _Float16* __restrict__ wt2,
        const _Float16* __restrict__ wt3,
        const float* __restrict__ b1, const float* __restrict__ b2,
        const float* __restrict__ b3,
        float* __restrict__ out, int blk) {
    constexpr int K1P = 96;
    constexpr int S1 = K1P + 8;
    constexpr int S2 = C1 + 8;
    constexpr int S3 = C2 + 8;
    constexpr int MT = M / 16;
    constexpr int NCH1 = C1 / 4, NCH2 = C2 / 4, NCH3 = C3 / 4;
    constexpr int NT1 = NCH1 / 16, NT2 = NCH2 / 16, NT3 = NCH3 / 16;
    constexpr int KT1 = K1P / 32, KT2 = C1 / 32, KT3 = C2 / 32;

    _Float16* feat = (_Float16*)smem;
    _Float16* h1 = feat + M * S1;
    _Float16* h2 = h1 + M * S2;
    int* outmax = (int*)(h2 + M * S3);

    const int tid = threadIdx.x;
    const int lane = tid & 63;
    const int w = tid >> 6;
    const int lm = lane & 15;
    const int lq = lane >> 4;

    f16x8 wf1[NT1][KT1], wf2[NT2][KT2], wf3[NT3][KT3];
    float bb1[NT1], bb2[NT2], bb3[NT3];
#pragma unroll
    for (int nt = 0; nt < NT1; ++nt) {
        int n = w * NCH1 + nt * 16 + lm;
        bb1[nt] = b1[n];
#pragma unroll
        for (int kt = 0; kt < KT1; ++kt)
            wf1[nt][kt] = *(const f16x8*)(wt1 + (size_t)n * K1P + kt * 32 + lq * 8);
    }
#pragma unroll
    for (int nt = 0; nt < NT2; ++nt) {
        int n = w * NCH2 + nt * 16 + lm;
        bb2[nt] = b2[n];
#pragma unroll
        for (int kt = 0; kt < KT2; ++kt)
            wf2[nt][kt] = *(const f16x8*)(wt2 + (size_t)n * C1 + kt * 32 + lq * 8);
    }
#pragma unroll
    for (int nt = 0; nt < NT3; ++nt) {
        int n = w * NCH3 + nt * 16 + lm;
        bb3[nt] = b3[n];
#pragma unroll
        for (int kt = 0; kt < KT3; ++kt)
            wf3[nt][kt] = *(const f16x8*)(wt3 + (size_t)n * C2 + kt * 32 + lq * 8);
    }

    for (int cc = 0; cc < NCTR; ++cc) {
        const int cid = blk * NCTR + cc;
        const int bidx = cid >> 10;
        const int nv = nvalid[cid];
        const float cx = centers[cid * 3 + 0];
        const float cy = centers[cid * 3 + 1];
        const float cz = centers[cid * 3 + 2];
        for (int i = tid; i < C3; i += 256) outmax[i] = 0;

#pragma unroll
        for (int it = tid; it < M * 16; it += 256) {
            const int r = it >> 4, sub = it & 15;
            if (r < nv) {
                int pt = nbr[(size_t)cid * M + r];
                float4 v = *(const float4*)(x + ((size_t)(bidx * NP) + pt) * 64 + sub * 4);
                f16x4 hv = {(_Float16)v.x, (_Float16)v.y, (_Float16)v.z, (_Float16)v.w};
                *(f16x4*)(feat + r * S1 + sub * 4) = hv;
            }
        }
#pragma unroll
        for (int it = tid; it < M * 4; it += 256) {
            const int r = it >> 2, q = it & 3;
            f16x8 z = {(_Float16)0.f, (_Float16)0.f, (_Float16)0.f, (_Float16)0.f,
                       (_Float16)0.f, (_Float16)0.f, (_Float16)0.f, (_Float16)0.f};
            if (q == 0 && r < nv) {
                int pt = nbr[(size_t)cid * M + r];
                const float* pr = pos + ((size_t)(bidx * NP) + pt) * 3;
                z[0] = (_Float16)(pr[0] - cx);
                z[1] = (_Float16)(pr[1] - cy);
                z[2] = (_Float16)(pr[2] - cz);
            }
            *(f16x8*)(feat + r * S1 + 64 + q * 8) = z;
        }
        __syncthreads();

#pragma unroll
        for (int mt = 0; mt < MT; ++mt) {
            f16x8 a[KT1];
#pragma unroll
            for (int kt = 0; kt < KT1; ++kt)
                a[kt] = *(const f16x8*)(feat + (mt * 16 + lm) * S1 + kt * 32 + lq * 8);
#pragma unroll
            for (int nt = 0; nt < NT1; ++nt) {
                f32x4 acc = {bb1[nt], bb1[nt], bb1[nt], bb1[nt]};
#pragma unroll
                for (int kt = 0; kt < KT1; ++kt)
                    acc = __builtin_amdgcn_mfma_f32_16x16x32_f16(a[kt], wf1[nt][kt], acc, 0, 0, 0);
                const int gc = w * NCH1 + nt * 16 + lm;
#pragma unroll
                for (int rg = 0; rg < 4; ++rg)
                    h1[(mt * 16 + lq * 4 + rg) * S2 + gc] = (_Float16)fmaxf(acc[rg], 0.f);
            }
        }
        __syncthreads();

#pragma unroll
        for (int mt = 0; mt < MT; ++mt) {
            f16x8 a[KT2];
#pragma unroll
            for (int kt = 0; kt < KT2; ++kt)
                a[kt] = *(const f16x8*)(h1 + (mt * 16 + lm) * S2 + kt * 32 + lq * 8);
#pragma unroll
            for (int nt = 0; nt < NT2; ++nt) {
                f32x4 acc = {bb2[nt], bb2[nt], bb2[nt], bb2[nt]};
#pragma unroll
                for (int kt = 0; kt < KT2; ++kt)
                    acc = __builtin_amdgcn_mfma_f32_16x16x32_f16(a[kt], wf2[nt][kt], acc, 0, 0, 0);
                const int gc = w * NCH2 + nt * 16 + lm;
#pragma unroll
                for (int rg = 0; rg < 4; ++rg)
                    h2[(mt * 16 + lq * 4 + rg) * S3 + gc] = (_Float16)fmaxf(acc[rg], 0.f);
            }
        }
        __syncthreads();

#pragma unroll
        for (int mt = 0; mt < MT; ++mt) {
            f16x8 a[KT3];
#pragma unroll
            for (int kt = 0; kt < KT3; ++kt)
                a[kt] = *(const f16x8*)(h2 + (mt * 16 + lm) * S3 + kt * 32 + lq * 8);
#pragma unroll
            for (int nt = 0; nt < NT3; ++nt) {
                f32x4 acc = {bb3[nt], bb3[nt], bb3[nt], bb3[nt]};
#pragma unroll
                for (int kt = 0; kt < KT3; ++kt)
                    acc = __builtin_amdgcn_mfma_f32_16x16x32_f16(a[kt], wf3[nt][kt], acc, 0, 0, 0);
                float mx = -1.f;
#pragma unroll
                for (int rg = 0; rg < 4; ++rg) {
                    int row = mt * 16 + lq * 4 + rg;
                    float v = fmaxf(acc[rg], 0.f);
                    if (row < nv) mx = fmaxf(mx, v);
                }
                mx = fmaxf(mx, __shfl_xor(mx, 16));
                mx = fmaxf(mx, __shfl_xor(mx, 32));
                if (lane < 16)
                    atomicMax(&outmax[w * NCH3 + nt * 16 + lm], __float_as_int(mx));
            }
        }
        __syncthreads();
        for (int i = tid; i < C3; i += 256)
            out[(size_t)cid * 640 + OFF + i] = __int_as_float(outmax[i]);
        __syncthreads();
    }
}

__global__ __launch_bounds__(256, 2) void mlp_seg0(
        const float* __restrict__ x, const float* __restrict__ pos,
        const float* __restrict__ centers,
        const int* __restrict__ nbr0, const int* __restrict__ nval,
        MlpW ww, float* __restrict__ out) {
    extern __shared__ char smem[];
    mlp_body<16, 64, 64, 128, 0, 8>(smem, x, pos, centers, nbr0, nval,
        ww.w[0], ww.w[1], ww.w[2], ww.bias[0], ww.bias[1], ww.bias[2],
        out, blockIdx.x);
}

// ========================= launcher ===========================
extern "C" void kernel_launch(void* const* d_in, const int* in_sizes, int n_in,
                              void* d_out, int out_size, void* d_ws, size_t ws_size,
                              hipStream_t stream) {
    const float* x = (const float*)d_in[0];
    const float* pos = (const float*)d_in[1];
    const float* W0_0 = (const float*)d_in[3];
    const float* b0_0 = (const float*)d_in[4];
    const float* W0_1 = (const float*)d_in[5];
    const float* b0_1 = (const float*)d_in[6];
    const float* W0_2 = (const float*)d_in[7];
    const float* b0_2 = (const float*)d_in[8];
    const float* W1_0 = (const float*)d_in[9];
    const float* b1_0 = (const float*)d_in[10];
    const float* W1_1 = (const float*)d_in[11];
    const float* b1_1 = (const float*)d_in[12];
    const float* W1_2 = (const float*)d_in[13];
    const float* b1_2 = (const float*)d_in[14];
    const float* W2_0 = (const float*)d_in[15];
    const float* b2_0 = (const float*)d_in[16];
    const float* W2_1 = (const float*)d_in[17];
    const float* b2_1 = (const float*)d_in[18];
    const float* W2_2 = (const float*)d_in[19];
    const float* b2_2 = (const float*)d_in[20];

    float* out = (float*)d_out;
    char* ws = (char*)d_ws;
    float* centers = (float*)(ws + 0);                 //  98304 B
    int* nbr0 = (int*)(ws + 98304);                    //  524288 B
    int* nbr1 = (int*)(ws + 622592);                   //  1048576 B
    int* nbr2 = (int*)(ws + 1671168);                  //  2097152 B
    int* nval = (int*)(ws + 3768320);                  //  98304 B
    _Float16* w0t1 = (_Float16*)(ws + 3866624);
    _Float16* w0t2 = (_Float16*)(ws + 3878912);
    _Float16* w0t3 = (_Float16*)(ws + 3887104);
    _Float16* w1t1 = (_Float16*)(ws + 3903488);
    _Float16* w1t2 = (_Float16*)(ws + 3928064);
    _Float16* w1t3 = (_Float16*)(ws + 3960832);
    _Float16* w2t1 = (_Float16*)(ws + 4026368);
    _Float16* w2t2 = (_Float16*)(ws + 4050944);
    _Float16* w2t3 = (_Float16*)(ws + 4083712);        // end 4149248 B
    unsigned* prog = (unsigned*)(ws + 4149248);        // 1024 B
    int* ready = (int*)(ws + 4150272);                 // 2*1024*4 = 8192 B

    float* out_pos = out + (size_t)8192 * 640;
    float* out_batch = out_pos + (size_t)8192 * 3;

    hipMemsetAsync(prog, 0, 1024 + 8192, stream);      // prog + ready contiguous

    PrepArgs pa;
    pa.src[0] = W0_0; pa.dst[0] = w0t1; pa.kr[0] = 67;  pa.kp[0] = 96;  pa.nc[0] = 64;
    pa.src[1] = W0_1; pa.dst[1] = w0t2; pa.kr[1] = 64;  pa.kp[1] = 64;  pa.nc[1] = 64;
    pa.src[2] = W0_2; pa.dst[2] = w0t3; pa.kr[2] = 64;  pa.kp[2] = 64;  pa.nc[2] = 128;
    pa.src[3] = W1_0; pa.dst[3] = w1t1; pa.kr[3] = 67;  pa.kp[3] = 96;  pa.nc[3] = 128;
    pa.src[4] = W1_1; pa.dst[4] = w1t2; pa.kr[4] = 128; pa.kp[4] = 128; pa.nc[4] = 128;
    pa.src[5] = W1_2; pa.dst[5] = w1t3; pa.kr[5] = 128; pa.kp[5] = 128; pa.nc[5] = 256;
    pa.src[6] = W2_0; pa.dst[6] = w2t1; pa.kr[6] = 67;  pa.kp[6] = 96;  pa.nc[6] = 128;
    pa.src[7] = W2_1; pa.dst[7] = w2t2; pa.kr[7] = 128; pa.kp[7] = 128; pa.nc[7] = 128;
    pa.src[8] = W2_2; pa.dst[8] = w2t3; pa.kr[8] = 128; pa.kp[8] = 128; pa.nc[8] = 256;

    MlpW ww;
    ww.w[0] = w0t1; ww.w[1] = w0t2; ww.w[2] = w0t3;
    ww.w[3] = w1t1; ww.w[4] = w1t2; ww.w[5] = w1t3;
    ww.w[6] = w2t1; ww.w[7] = w2t2; ww.w[8] = w2t3;
    ww.bias[0] = b0_0; ww.bias[1] = b0_1; ww.bias[2] = b0_2;
    ww.bias[3] = b1_0; ww.bias[4] = b1_1; ww.bias[5] = b1_2;
    ww.bias[6] = b2_0; ww.bias[7] = b2_1; ww.bias[8] = b2_2;

    // dynamic LDS = seg2 mlp footprint: 64*104*2 + 64*136*2*2 + 256*4 = 49152
    fps_select_mlp<<<dim3(256), dim3(512), 49152, stream>>>(
        pos, centers, out_pos, out_batch, nbr0, nbr1, nbr2, nval,
        prog, ready, x, out, pa, ww);

    // seg0 mlp: LDS = 16*104*2 + 16*72*2*2 + 128*4 = 8448 B
    mlp_seg0<<<dim3(1024), dim3(256), 8448, stream>>>(
        x, pos, centers, nbr0, nval, ww, out);
}

// Round 9
// 2076.540 us; speedup vs baseline: 2.9981x; 2.9981x over previous
//
#include <hip/hip_runtime.h>

#define NB 8
#define NP 4096
#define NS 1024
#define PROGSTRIDE 32   // one 128B cache line per cloud's progress word
#define SELB 120        // select blocks (960 waves: 2.5x margin over 295k wave-us)
#define NUNIT 3072      // (1024/8 s-octets) x 3 segs x 8 clouds

typedef _Float16 f16x8 __attribute__((ext_vector_type(8)));
typedef _Float16 f16x4 __attribute__((ext_vector_type(4)));
typedef float f32x4 __attribute__((ext_vector_type(4)));

// DPP-fused max step: v = max(v, dpp_move(v, ctrl)). bound_ctrl=false keeps
// old value on invalid lanes -> max(v,v)=v, harmless.
#define DPP_MAX(v, ctrl)                                                     \
    v = fmaxf(v, __int_as_float(__builtin_amdgcn_update_dpp(                 \
                __float_as_int(v), __float_as_int(v), (ctrl), 0xf, 0xf, false)))

struct PrepArgs {
    const float* src[9];
    _Float16* dst[9];
    int kr[9], kp[9], nc[9];
};

struct MlpW {
    const _Float16* w[9];
    const float* bias[9];
};

// ========================= Selection body ==========================
// ROUND-7 kernel (measured win). Early-exit binary search on uint(d2) bits,
// no LDS staging, one center per wave. Bit-identical to exact top-k.
template <int K>
__device__ __forceinline__ void select_center(
        const float* __restrict__ pb,
        const float* __restrict__ centers,
        int* __restrict__ nbr, int* __restrict__ nvalid,
        float r2, int scid) {
#pragma clang fp contract(off)
    const int lane = threadIdx.x & 63;
    const unsigned kr2 = __float_as_uint(r2);
    const float cx = centers[scid * 3 + 0];
    const float cy = centers[scid * 3 + 1];
    const float cz = centers[scid * 3 + 2];

    unsigned key[64];
#pragma unroll
    for (int i = 0; i < 64; ++i) {
        const float* pp = pb + (size_t)(lane + i * 64) * 3;
        float dx = pp[0] - cx; float sx = dx * dx;
        float dy = pp[1] - cy; float sy = dy * dy;
        float dz = pp[2] - cz; float sz = dz * dz;
        float d2 = sx + sy; d2 = d2 + sz;
        key[i] = __float_as_uint(d2);
    }

    const unsigned long long below = (1ull << lane) - 1ull;
    int c_cnt = 0;
#pragma unroll
    for (int i = 0; i < 64; ++i)
        c_cnt += __popcll(__ballot(key[i] <= kr2));

    unsigned thr = kr2;
    int nv = c_cnt;
    bool need_ties = false;
    unsigned tkey = 0;
    if (c_cnt > K) {
        nv = K;
        unsigned lo = 0, hi = kr2;
        need_ties = true;
        while (lo < hi) {
            unsigned mid = lo + ((hi - lo) >> 1);
            int cnt = 0;
#pragma unroll
            for (int i = 0; i < 64; ++i)
                cnt += __popcll(__ballot(key[i] <= mid));
            if (cnt == K) { thr = mid; need_ties = false; break; }
            if (cnt > K) hi = mid; else lo = mid + 1;
        }
        tkey = lo;
    }

    if (!need_ties) {
        int base = 0;
#pragma unroll
        for (int i = 0; i < 64; ++i) {
            unsigned long long m = __ballot(key[i] <= thr);
            if (key[i] <= thr)
                nbr[(size_t)scid * K + base + __popcll(m & below)] = lane + i * 64;
            base += __popcll(m);
        }
    } else {
        const unsigned t = tkey;
        int m_cnt = 0;
#pragma unroll
        for (int i = 0; i < 64; ++i)
            m_cnt += __popcll(__ballot(key[i] < t));
        const int rem = K - m_cnt;
        int base = 0, tcnt = 0;
#pragma unroll
        for (int i = 0; i < 64; ++i) {
            unsigned long long lt = __ballot(key[i] < t);
            unsigned long long eq = __ballot(key[i] == t);
            if (key[i] < t) {
                nbr[(size_t)scid * K + base + __popcll(lt & below)] = lane + i * 64;
            } else if (key[i] == t) {
                int tr = tcnt + __popcll(eq & below);
                if (tr < rem) nbr[(size_t)scid * K + (m_cnt + tr)] = lane + i * 64;
            }
            base += __popcll(lt);
            tcnt += __popcll(eq);
        }
    }
    if (lane == 0) nvalid[scid] = nv;
}

// =================== MLP unit body (one 8-center unit) =====================
// AW = active waves (8 for seg1/2, 4 for seg0 since C1=64 gives 16 cols/wave
// only with a 4-way split). Inactive waves still hit every barrier. Same
// per-output arithmetic as the proven 4-wave mlp_body -> bit-identical.
template <int M, int C1, int C2, int C3, int OFF, int AW>
__device__ void mlp_unit(
        char* smem,
        const float* __restrict__ x, const float* __restrict__ pos,
        const float* __restrict__ centers,
        const int* __restrict__ nbr, const int* __restrict__ nvalid,
        const _Float16* __restrict__ wt1, const _Float16* __restrict__ wt2,
        const _Float16* __restrict__ wt3,
        const float* __restrict__ b1, const float* __restrict__ b2,
        const float* __restrict__ b3,
        float* __restrict__ out, int cid0) {
    constexpr int K1P = 96;
    constexpr int S1 = K1P + 8;
    constexpr int S2 = C1 + 8;
    constexpr int S3 = C2 + 8;
    constexpr int MT = M / 16;
    constexpr int NCH1 = C1 / AW, NCH2 = C2 / AW, NCH3 = C3 / AW;
    constexpr int NT1 = NCH1 / 16, NT2 = NCH2 / 16, NT3 = NCH3 / 16;
    constexpr int KT1 = K1P / 32, KT2 = C1 / 32, KT3 = C2 / 32;

    _Float16* feat = (_Float16*)smem;
    _Float16* h1 = feat + M * S1;
    _Float16* h2 = h1 + M * S2;
    int* outmax = (int*)(h2 + M * S3);

    const int tid = threadIdx.x;
    const int lane = tid & 63;
    const int w = tid >> 6;
    const int lm = lane & 15;
    const int lq = lane >> 4;
    const bool act = (w < AW);

    f16x8 wf1[NT1][KT1], wf2[NT2][KT2], wf3[NT3][KT3];
    float bb1[NT1], bb2[NT2], bb3[NT3];
    if (act) {
#pragma unroll
        for (int nt = 0; nt < NT1; ++nt) {
            int n = w * NCH1 + nt * 16 + lm;
            bb1[nt] = b1[n];
#pragma unroll
            for (int kt = 0; kt < KT1; ++kt)
                wf1[nt][kt] = *(const f16x8*)(wt1 + (size_t)n * K1P + kt * 32 + lq * 8);
        }
#pragma unroll
        for (int nt = 0; nt < NT2; ++nt) {
            int n = w * NCH2 + nt * 16 + lm;
            bb2[nt] = b2[n];
#pragma unroll
            for (int kt = 0; kt < KT2; ++kt)
                wf2[nt][kt] = *(const f16x8*)(wt2 + (size_t)n * C1 + kt * 32 + lq * 8);
        }
#pragma unroll
        for (int nt = 0; nt < NT3; ++nt) {
            int n = w * NCH3 + nt * 16 + lm;
            bb3[nt] = b3[n];
#pragma unroll
            for (int kt = 0; kt < KT3; ++kt)
                wf3[nt][kt] = *(const f16x8*)(wt3 + (size_t)n * C2 + kt * 32 + lq * 8);
        }
    }

    for (int cc = 0; cc < 8; ++cc) {
        const int cid = cid0 + cc;
        const int bidx = cid >> 10;
        const int nv = nvalid[cid];
        const float cx = centers[cid * 3 + 0];
        const float cy = centers[cid * 3 + 1];
        const float cz = centers[cid * 3 + 2];
        for (int i = tid; i < C3; i += 512) outmax[i] = 0;

        // gather A: x features (stale rows masked at layer 3)
        for (int it = tid; it < M * 16; it += 512) {
            const int r = it >> 4, sub = it & 15;
            if (r < nv) {
                int pt = nbr[(size_t)cid * M + r];
                float4 v = *(const float4*)(x + ((size_t)(bidx * NP) + pt) * 64 + sub * 4);
                f16x4 hv = {(_Float16)v.x, (_Float16)v.y, (_Float16)v.z, (_Float16)v.w};
                *(f16x4*)(feat + r * S1 + sub * 4) = hv;
            }
        }
        // gather B: pos-rel + zero K-pad
        for (int it = tid; it < M * 4; it += 512) {
            const int r = it >> 2, q = it & 3;
            f16x8 z = {(_Float16)0.f, (_Float16)0.f, (_Float16)0.f, (_Float16)0.f,
                       (_Float16)0.f, (_Float16)0.f, (_Float16)0.f, (_Float16)0.f};
            if (q == 0 && r < nv) {
                int pt = nbr[(size_t)cid * M + r];
                const float* pr = pos + ((size_t)(bidx * NP) + pt) * 3;
                z[0] = (_Float16)(pr[0] - cx);
                z[1] = (_Float16)(pr[1] - cy);
                z[2] = (_Float16)(pr[2] - cz);
            }
            *(f16x8*)(feat + r * S1 + 64 + q * 8) = z;
        }
        __syncthreads();

        // layer 1
        if (act) {
#pragma unroll
            for (int mt = 0; mt < MT; ++mt) {
                f16x8 a[KT1];
#pragma unroll
                for (int kt = 0; kt < KT1; ++kt)
                    a[kt] = *(const f16x8*)(feat + (mt * 16 + lm) * S1 + kt * 32 + lq * 8);
#pragma unroll
                for (int nt = 0; nt < NT1; ++nt) {
                    f32x4 acc = {bb1[nt], bb1[nt], bb1[nt], bb1[nt]};
#pragma unroll
                    for (int kt = 0; kt < KT1; ++kt)
                        acc = __builtin_amdgcn_mfma_f32_16x16x32_f16(a[kt], wf1[nt][kt], acc, 0, 0, 0);
                    const int gc = w * NCH1 + nt * 16 + lm;
#pragma unroll
                    for (int rg = 0; rg < 4; ++rg)
                        h1[(mt * 16 + lq * 4 + rg) * S2 + gc] = (_Float16)fmaxf(acc[rg], 0.f);
                }
            }
        }
        __syncthreads();

        // layer 2
        if (act) {
#pragma unroll
            for (int mt = 0; mt < MT; ++mt) {
                f16x8 a[KT2];
#pragma unroll
                for (int kt = 0; kt < KT2; ++kt)
                    a[kt] = *(const f16x8*)(h1 + (mt * 16 + lm) * S2 + kt * 32 + lq * 8);
#pragma unroll
                for (int nt = 0; nt < NT2; ++nt) {
                    f32x4 acc = {bb2[nt], bb2[nt], bb2[nt], bb2[nt]};
#pragma unroll
                    for (int kt = 0; kt < KT2; ++kt)
                        acc = __builtin_amdgcn_mfma_f32_16x16x32_f16(a[kt], wf2[nt][kt], acc, 0, 0, 0);
                    const int gc = w * NCH2 + nt * 16 + lm;
#pragma unroll
                    for (int rg = 0; rg < 4; ++rg)
                        h2[(mt * 16 + lq * 4 + rg) * S3 + gc] = (_Float16)fmaxf(acc[rg], 0.f);
                }
            }
        }
        __syncthreads();

        // layer 3 + masked max
        if (act) {
#pragma unroll
            for (int mt = 0; mt < MT; ++mt) {
                f16x8 a[KT3];
#pragma unroll
                for (int kt = 0; kt < KT3; ++kt)
                    a[kt] = *(const f16x8*)(h2 + (mt * 16 + lm) * S3 + kt * 32 + lq * 8);
#pragma unroll
                for (int nt = 0; nt < NT3; ++nt) {
                    f32x4 acc = {bb3[nt], bb3[nt], bb3[nt], bb3[nt]};
#pragma unroll
                    for (int kt = 0; kt < KT3; ++kt)
                        acc = __builtin_amdgcn_mfma_f32_16x16x32_f16(a[kt], wf3[nt][kt], acc, 0, 0, 0);
                    float mx = -1.f;
#pragma unroll
                    for (int rg = 0; rg < 4; ++rg) {
                        int row = mt * 16 + lq * 4 + rg;
                        float v = fmaxf(acc[rg], 0.f);
                        if (row < nv) mx = fmaxf(mx, v);
                    }
                    mx = fmaxf(mx, __shfl_xor(mx, 16));
                    mx = fmaxf(mx, __shfl_xor(mx, 32));
                    if (lane < 16)
                        atomicMax(&outmax[w * NCH3 + nt * 16 + lm], __float_as_int(mx));
                }
            }
        }
        __syncthreads();
        for (int i = tid; i < C3; i += 512)
            out[(size_t)cid * 640 + OFF + i] = __int_as_float(outmax[i]);
        __syncthreads();
    }
}

// ====== UBER KERNEL: fps (8) -> select (120) -> mlp (128), one launch ======
// ROUND-12. R7's failure isolated: select starved at 256 waves (96 latency-
// bound tasks/wave). Correct provisioning from measured work: select 295k
// wave-us -> 960 waves (31% util); mlp 635k wave-us -> 1024 waves, fed by a
// GLOBAL claim queue ordered (s-octet, seg, cloud) == readiness order, so
// claimed units are ready within ~20us of fps. seg0 runs in-kernel with a
// 4-active-wave unit. Per-task signal: wave drains stores (vmcnt 0) then
// lane0 release-adds ready[q] (R4-proven agent-scope protocol).
// DEADLOCK-FREE DAG: fps waits on nothing; select waits only on prog (fps);
// mlp waits only on ready (select). 256 blocks, 1/CU, all resident.
__global__ __launch_bounds__(512, 1) void fps_select_mlp(
        const float* __restrict__ pos,
        float* __restrict__ centers,
        float* __restrict__ out_pos,
        float* __restrict__ out_batch,
        int* __restrict__ nbr0, int* __restrict__ nbr1, int* __restrict__ nbr2,
        int* __restrict__ nval,
        unsigned* __restrict__ prog,
        int* __restrict__ ready,          // [NUNIT]
        int* __restrict__ mlp_next,
        const float* __restrict__ x,
        float* __restrict__ out,
        PrepArgs pa, MlpW ww) {
#pragma clang fp contract(off)
    extern __shared__ char smem[];
    const int tid = threadIdx.x;
    const int lane = tid & 63;
    const int blk = blockIdx.x;

    if (blk < NB) {
        // ------------------------ producer: FPS (R6-identical) --------------
        const int b = blk;
        const int wid = tid >> 6;
        __shared__ float4 slot[2][8];

        const float* pb = pos + (size_t)b * NP * 3;
        float px[8], py[8], pz[8], md[8];
        {
            const float4* pv = (const float4*)(pb + tid * 24);
            float4 q0 = pv[0], q1 = pv[1], q2 = pv[2];
            float4 q3 = pv[3], q4 = pv[4], q5 = pv[5];
            px[0] = q0.x; py[0] = q0.y; pz[0] = q0.z;
            px[1] = q0.w; py[1] = q1.x; pz[1] = q1.y;
            px[2] = q1.z; py[2] = q1.w; pz[2] = q2.x;
            px[3] = q2.y; py[3] = q2.z; pz[3] = q2.w;
            px[4] = q3.x; py[4] = q3.y; pz[4] = q3.z;
            px[5] = q3.w; py[5] = q4.x; pz[5] = q4.y;
            px[6] = q4.z; py[6] = q4.w; pz[6] = q5.x;
            px[7] = q5.y; py[7] = q5.z; pz[7] = q5.w;
        }
#pragma unroll
        for (int j = 0; j < 8; ++j) md[j] = __builtin_inff();
        for (int t = tid; t < NS; t += 512) out_batch[b * NS + t] = (float)b;

        float cx = pb[0], cy = pb[1], cz = pb[2];
        if (tid == 0) {
            size_t o = (size_t)(b * NS) * 3;
            centers[o + 0] = cx; centers[o + 1] = cy; centers[o + 2] = cz;
            out_pos[o + 0] = cx; out_pos[o + 1] = cy; out_pos[o + 2] = cz;
        }

        int par = 0;
        for (int t = 1; t < NS; ++t) {
            float bv = -1.0f, bx = cx, by = cy, bz = cz;
#pragma unroll
            for (int j = 0; j < 8; ++j) {
                float dx = px[j] - cx; float sx = dx * dx;
                float dy = py[j] - cy; float sy = dy * dy;
                float dz = pz[j] - cz; float sz = dz * dz;
                float d = sx + sy; d = d + sz;
                float m = fminf(md[j], d);
                md[j] = m;
                bool c = m > bv;
                bv = c ? m : bv;
                bx = c ? px[j] : bx;
                by = c ? py[j] : by;
                bz = c ? pz[j] : bz;
            }
            float v = bv;
            DPP_MAX(v, 0x111);
            DPP_MAX(v, 0x112);
            DPP_MAX(v, 0x114);
            DPP_MAX(v, 0x118);
            DPP_MAX(v, 0x142);
            DPP_MAX(v, 0x143);
            const float mx = __int_as_float(
                __builtin_amdgcn_readlane(__float_as_int(v), 63));
            unsigned long long tie = __ballot(bv == mx);
            if (lane == __ffsll(tie) - 1)
                slot[par][wid] = make_float4(mx, bx, by, bz);
            __syncthreads();
            float4 s0 = slot[par][0], s1 = slot[par][1];
            float4 s2 = slot[par][2], s3 = slot[par][3];
            float4 s4 = slot[par][4], s5 = slot[par][5];
            float4 s6 = slot[par][6], s7 = slot[par][7];
            float4 a01 = (s1.x > s0.x) ? s1 : s0;
            float4 a23 = (s3.x > s2.x) ? s3 : s2;
            float4 a45 = (s5.x > s4.x) ? s5 : s4;
            float4 a67 = (s7.x > s6.x) ? s7 : s6;
            float4 b03 = (a23.x > a01.x) ? a23 : a01;
            float4 b47 = (a67.x > a45.x) ? a67 : a45;
            float4 wn = (b47.x > b03.x) ? b47 : b03;
            cx = wn.y; cy = wn.z; cz = wn.w;
            if (tid == 0) {
                size_t o = (size_t)(b * NS + t) * 3;
                centers[o + 0] = cx; centers[o + 1] = cy; centers[o + 2] = cz;
                out_pos[o + 0] = cx; out_pos[o + 1] = cy; out_pos[o + 2] = cz;
                if ((t & 15) == 15)
                    __hip_atomic_store(&prog[b * PROGSTRIDE], (unsigned)(t + 1),
                                       __ATOMIC_RELEASE, __HIP_MEMORY_SCOPE_AGENT);
            }
            par ^= 1;
        }
    } else if (blk < NB + SELB) {
        // ------------------------ select workers ----------------------------
        const int wblk = blk - NB;               // 0..119
        const int wid = tid >> 6;                // 0..7
        const int wave_id = wblk * 8 + wid;      // 0..959
        const int NWAVE = SELB * 8;              // 960
        const int NTASK = 3 * NB * NS;           // 24576
        for (int T = wave_id; T < NTASK; T += NWAVE) {
            const int s = T / 24;
            const int r = T - s * 24;
            const int b = r & 7;
            const int seg = r >> 3;
            const int scid = b * NS + s;
            while (__hip_atomic_load(&prog[b * PROGSTRIDE], __ATOMIC_ACQUIRE,
                                     __HIP_MEMORY_SCOPE_AGENT) <= (unsigned)s)
                __builtin_amdgcn_s_sleep(32);
            const float* pb = pos + (size_t)b * NP * 3;
            if (seg == 0)
                select_center<16>(pb, centers, nbr0, nval,
                                  (float)(0.1 * 0.1), scid);
            else if (seg == 1)
                select_center<32>(pb, centers, nbr1, nval + 8192,
                                  (float)(0.2 * 0.2), scid);
            else
                select_center<64>(pb, centers, nbr2, nval + 16384,
                                  (float)(0.4 * 0.4), scid);
            // drain this wave's nbr/nval stores, then signal the unit
            asm volatile("s_waitcnt vmcnt(0)" ::: "memory");
            if (lane == 0)
                __hip_atomic_fetch_add(&ready[(s >> 3) * 24 + (seg << 3) + b], 1,
                                       __ATOMIC_RELEASE, __HIP_MEMORY_SCOPE_AGENT);
        }
    } else {
        // ------------------------ mlp workers -------------------------------
        // redundant idempotent weight prep (128x; 248x measured neutral, R6)
        {
#pragma unroll 1
            for (int m = 0; m < 9; ++m) {
                const int kp = pa.kp[m], kr = pa.kr[m], nc = pa.nc[m];
                const float* src = pa.src[m];
                _Float16* dst = pa.dst[m];
                const int tot = kp * nc;
                for (int i = tid; i < tot; i += 512) {
                    int n = i / kp, k = i - n * kp;
                    dst[i] = (k < kr) ? (_Float16)src[(size_t)k * nc + n]
                                      : (_Float16)0.f;
                }
            }
            __syncthreads();   // drains vmcnt; own stores visible via own L2
        }
        __shared__ int sh_u;
        for (;;) {
            if (tid == 0)
                sh_u = __hip_atomic_fetch_add(mlp_next, 1, __ATOMIC_RELAXED,
                                              __HIP_MEMORY_SCOPE_AGENT);
            __syncthreads();
            const int u = sh_u;
            if (u >= NUNIT) break;
            while (__hip_atomic_load(&ready[u], __ATOMIC_ACQUIRE,
                                     __HIP_MEMORY_SCOPE_AGENT) < 8)
                __builtin_amdgcn_s_sleep(16);
            const int su = u / 24;
            const int rem = u - su * 24;
            const int seg = rem >> 3;
            const int b = rem & 7;
            const int cid0 = b * NS + su * 8;
            if (seg == 0)
                mlp_unit<16, 64, 64, 128, 0, 4>(smem, x, pos, centers,
                    nbr0, nval, ww.w[0], ww.w[1], ww.w[2],
                    ww.bias[0], ww.bias[1], ww.bias[2], out, cid0);
            else if (seg == 1)
                mlp_unit<32, 128, 128, 256, 128, 8>(smem, x, pos, centers,
                    nbr1, nval + 8192, ww.w[3], ww.w[4], ww.w[5],
                    ww.bias[3], ww.bias[4], ww.bias[5], out, cid0);
            else
                mlp_unit<64, 128, 128, 256, 384, 8>(smem, x, pos, centers,
                    nbr2, nval + 16384, ww.w[6], ww.w[7], ww.w[8],
                    ww.bias[6], ww.bias[7], ww.bias[8], out, cid0);
            // mlp_unit ends with __syncthreads -> safe to overwrite sh_u
        }
    }
}

// ========================= launcher ===========================
extern "C" void kernel_launch(void* const* d_in, const int* in_sizes, int n_in,
                              void* d_out, int out_size, void* d_ws, size_t ws_size,
                              hipStream_t stream) {
    const float* x = (const float*)d_in[0];
    const float* pos = (const float*)d_in[1];
    const float* W0_0 = (const float*)d_in[3];
    const float* b0_0 = (const float*)d_in[4];
    const float* W0_1 = (const float*)d_in[5];
    const float* b0_1 = (const float*)d_in[6];
    const float* W0_2 = (const float*)d_in[7];
    const float* b0_2 = (const float*)d_in[8];
    const float* W1_0 = (const float*)d_in[9];
    const float* b1_0 = (const float*)d_in[10];
    const float* W1_1 = (const float*)d_in[11];
    const float* b1_1 = (const float*)d_in[12];
    const float* W1_2 = (const float*)d_in[13];
    const float* b1_2 = (const float*)d_in[14];
    const float* W2_0 = (const float*)d_in[15];
    const float* b2_0 = (const float*)d_in[16];
    const float* W2_1 = (const float*)d_in[17];
    const float* b2_1 = (const float*)d_in[18];
    const float* W2_2 = (const float*)d_in[19];
    const float* b2_2 = (const float*)d_in[20];

    float* out = (float*)d_out;
    char* ws = (char*)d_ws;
    float* centers = (float*)(ws + 0);                 //  98304 B
    int* nbr0 = (int*)(ws + 98304);                    //  524288 B
    int* nbr1 = (int*)(ws + 622592);                   //  1048576 B
    int* nbr2 = (int*)(ws + 1671168);                  //  2097152 B
    int* nval = (int*)(ws + 3768320);                  //  98304 B
    _Float16* w0t1 = (_Float16*)(ws + 3866624);
    _Float16* w0t2 = (_Float16*)(ws + 3878912);
    _Float16* w0t3 = (_Float16*)(ws + 3887104);
    _Float16* w1t1 = (_Float16*)(ws + 3903488);
    _Float16* w1t2 = (_Float16*)(ws + 3928064);
    _Float16* w1t3 = (_Float16*)(ws + 3960832);
    _Float16* w2t1 = (_Float16*)(ws + 4026368);
    _Float16* w2t2 = (_Float16*)(ws + 4050944);
    _Float16* w2t3 = (_Float16*)(ws + 4083712);        // end 4149248 B
    unsigned* prog = (unsigned*)(ws + 4149248);        // 1024 B
    int* ready = (int*)(ws + 4150272);                 // 3072*4 = 12288 B
    int* mlp_next = (int*)(ws + 4162560);              // 4 B

    float* out_pos = out + (size_t)8192 * 640;
    float* out_batch = out_pos + (size_t)8192 * 3;

    hipMemsetAsync(prog, 0, 1024 + 12288 + 4, stream); // prog+ready+mlp_next

    PrepArgs pa;
    pa.src[0] = W0_0; pa.dst[0] = w0t1; pa.kr[0] = 67;  pa.kp[0] = 96;  pa.nc[0] = 64;
    pa.src[1] = W0_1; pa.dst[1] = w0t2; pa.kr[1] = 64;  pa.kp[1] = 64;  pa.nc[1] = 64;
    pa.src[2] = W0_2; pa.dst[2] = w0t3; pa.kr[2] = 64;  pa.kp[2] = 64;  pa.nc[2] = 128;
    pa.src[3] = W1_0; pa.dst[3] = w1t1; pa.kr[3] = 67;  pa.kp[3] = 96;  pa.nc[3] = 128;
    pa.src[4] = W1_1; pa.dst[4] = w1t2; pa.kr[4] = 128; pa.kp[4] = 128; pa.nc[4] = 128;
    pa.src[5] = W1_2; pa.dst[5] = w1t3; pa.kr[5] = 128; pa.kp[5] = 128; pa.nc[5] = 256;
    pa.src[6] = W2_0; pa.dst[6] = w2t1; pa.kr[6] = 67;  pa.kp[6] = 96;  pa.nc[6] = 128;
    pa.src[7] = W2_1; pa.dst[7] = w2t2; pa.kr[7] = 128; pa.kp[7] = 128; pa.nc[7] = 128;
    pa.src[8] = W2_2; pa.dst[8] = w2t3; pa.kr[8] = 128; pa.kp[8] = 128; pa.nc[8] = 256;

    MlpW ww;
    ww.w[0] = w0t1; ww.w[1] = w0t2; ww.w[2] = w0t3;
    ww.w[3] = w1t1; ww.w[4] = w1t2; ww.w[5] = w1t3;
    ww.w[6] = w2t1; ww.w[7] = w2t2; ww.w[8] = w2t3;
    ww.bias[0] = b0_0; ww.bias[1] = b0_1; ww.bias[2] = b0_2;
    ww.bias[3] = b1_0; ww.bias[4] = b1_1; ww.bias[5] = b1_2;
    ww.bias[6] = b2_0; ww.bias[7] = b2_1; ww.bias[8] = b2_2;

    // dynamic LDS = seg2 mlp footprint: 64*104*2 + 64*136*2*2 + 256*4 = 49152
    fps_select_mlp<<<dim3(256), dim3(512), 49152, stream>>>(
        pos, centers, out_pos, out_batch, nbr0, nbr1, nbr2, nval,
        prog, ready, mlp_next, x, out, pa, ww);
}

// Round 10
// 1115.474 us; speedup vs baseline: 5.5813x; 1.8616x over previous
//
#include <hip/hip_runtime.h>

#define NB 8
#define NP 4096
#define NS 1024
#define PROGSTRIDE 32   // one 128B cache line per cloud's progress word

typedef _Float16 f16x8 __attribute__((ext_vector_type(8)));
typedef _Float16 f16x4 __attribute__((ext_vector_type(4)));
typedef float f32x4 __attribute__((ext_vector_type(4)));

// DPP-fused max step: v = max(v, dpp_move(v, ctrl)). bound_ctrl=false keeps
// old value on invalid lanes -> max(v,v)=v, harmless.
#define DPP_MAX(v, ctrl)                                                     \
    v = fmaxf(v, __int_as_float(__builtin_amdgcn_update_dpp(                 \
                __float_as_int(v), __float_as_int(v), (ctrl), 0xf, 0xf, false)))

struct PrepArgs {
    const float* src[9];
    _Float16* dst[9];
    int kr[9], kp[9], nc[9];
};

// ========================= Selection body ==========================
// Early-exit binary search on uint(d2) bits, no LDS staging, one center per
// wave. Bit-identical to exact top-k (tie path kept as fallback). FROZEN.
template <int K>
__device__ __forceinline__ void select_center(
        const float* __restrict__ pb,
        const float* __restrict__ centers,
        int* __restrict__ nbr, int* __restrict__ nvalid,
        float r2, int scid) {
#pragma clang fp contract(off)
    const int lane = threadIdx.x & 63;
    const unsigned kr2 = __float_as_uint(r2);
    const float cx = centers[scid * 3 + 0];
    const float cy = centers[scid * 3 + 1];
    const float cz = centers[scid * 3 + 2];

    unsigned key[64];
#pragma unroll
    for (int i = 0; i < 64; ++i) {
        const float* pp = pb + (size_t)(lane + i * 64) * 3;
        float dx = pp[0] - cx; float sx = dx * dx;
        float dy = pp[1] - cy; float sy = dy * dy;
        float dz = pp[2] - cz; float sz = dz * dz;
        float d2 = sx + sy; d2 = d2 + sz;
        key[i] = __float_as_uint(d2);
    }

    const unsigned long long below = (1ull << lane) - 1ull;
    int c_cnt = 0;
#pragma unroll
    for (int i = 0; i < 64; ++i)
        c_cnt += __popcll(__ballot(key[i] <= kr2));

    unsigned thr = kr2;          // threshold for the no-ties write pass
    int nv = c_cnt;
    bool need_ties = false;
    unsigned tkey = 0;
    if (c_cnt > K) {
        nv = K;
        unsigned lo = 0, hi = kr2;
        need_ties = true;
        while (lo < hi) {
            unsigned mid = lo + ((hi - lo) >> 1);
            int cnt = 0;
#pragma unroll
            for (int i = 0; i < 64; ++i)
                cnt += __popcll(__ballot(key[i] <= mid));
            if (cnt == K) { thr = mid; need_ties = false; break; }
            if (cnt > K) hi = mid; else lo = mid + 1;
        }
        tkey = lo;               // only meaningful if need_ties
    }

    if (!need_ties) {
        int base = 0;
#pragma unroll
        for (int i = 0; i < 64; ++i) {
            unsigned long long m = __ballot(key[i] <= thr);
            if (key[i] <= thr)
                nbr[(size_t)scid * K + base + __popcll(m & below)] = lane + i * 64;
            base += __popcll(m);
        }
    } else {
        const unsigned t = tkey;
        int m_cnt = 0;
#pragma unroll
        for (int i = 0; i < 64; ++i)
            m_cnt += __popcll(__ballot(key[i] < t));
        const int rem = K - m_cnt;
        int base = 0, tcnt = 0;
#pragma unroll
        for (int i = 0; i < 64; ++i) {
            unsigned long long lt = __ballot(key[i] < t);
            unsigned long long eq = __ballot(key[i] == t);
            if (key[i] < t) {
                nbr[(size_t)scid * K + base + __popcll(lt & below)] = lane + i * 64;
            } else if (key[i] == t) {
                int tr = tcnt + __popcll(eq & below);
                if (tr < rem) nbr[(size_t)scid * K + (m_cnt + tr)] = lane + i * 64;
            }
            base += __popcll(lt);
            tcnt += __popcll(eq);
        }
    }
    if (lane == 0) nvalid[scid] = nv;
}

// ================== FUSED FPS (producers) + SELECT (consumers) ==============
// ROUND-6 MEASURED-GOOD (1118.7us total; fused dispatch ~800us). Reverted
// here verbatim after R7/R9's triple-fusion regressed to 2077us: static
// role partitions starve mlp (1 block/CU exposes gather latency; role-done
// CUs idle). fps 8 blocks + 248 select worker blocks (1984 waves), prep in
// worker preamble, padded prog lines, s_sleep(32), cadence-16 publish.
__global__ __launch_bounds__(512, 1) void fps_select_fused(
        const float* __restrict__ pos,
        float* __restrict__ centers,
        float* __restrict__ out_pos,
        float* __restrict__ out_batch,
        int* __restrict__ nbr0, int* __restrict__ nbr1, int* __restrict__ nbr2,
        int* __restrict__ nval,
        unsigned* __restrict__ prog,
        PrepArgs pa) {
#pragma clang fp contract(off)
    const int tid = threadIdx.x;
    const int lane = tid & 63;

    if (blockIdx.x < NB) {
        // ------------------------ producer: FPS ------------------------
        const int b = blockIdx.x;
        const int wid = tid >> 6;
        __shared__ float4 slot[2][8];   // [parity][wave]

        const float* pb = pos + (size_t)b * NP * 3;
        float px[8], py[8], pz[8], md[8];
        {
            const float4* pv = (const float4*)(pb + tid * 24);
            float4 q0 = pv[0], q1 = pv[1], q2 = pv[2];
            float4 q3 = pv[3], q4 = pv[4], q5 = pv[5];
            px[0] = q0.x; py[0] = q0.y; pz[0] = q0.z;
            px[1] = q0.w; py[1] = q1.x; pz[1] = q1.y;
            px[2] = q1.z; py[2] = q1.w; pz[2] = q2.x;
            px[3] = q2.y; py[3] = q2.z; pz[3] = q2.w;
            px[4] = q3.x; py[4] = q3.y; pz[4] = q3.z;
            px[5] = q3.w; py[5] = q4.x; pz[5] = q4.y;
            px[6] = q4.z; py[6] = q4.w; pz[6] = q5.x;
            px[7] = q5.y; py[7] = q5.z; pz[7] = q5.w;
        }
#pragma unroll
        for (int j = 0; j < 8; ++j) md[j] = __builtin_inff();
        for (int t = tid; t < NS; t += 512) out_batch[b * NS + t] = (float)b;

        float cx = pb[0], cy = pb[1], cz = pb[2];
        if (tid == 0) {
            size_t o = (size_t)(b * NS) * 3;
            centers[o + 0] = cx; centers[o + 1] = cy; centers[o + 2] = cz;
            out_pos[o + 0] = cx; out_pos[o + 1] = cy; out_pos[o + 2] = cz;
        }

        int par = 0;
        for (int t = 1; t < NS; ++t) {
            float bv = -1.0f, bx = cx, by = cy, bz = cz;
#pragma unroll
            for (int j = 0; j < 8; ++j) {
                float dx = px[j] - cx; float sx = dx * dx;
                float dy = py[j] - cy; float sy = dy * dy;
                float dz = pz[j] - cz; float sz = dz * dz;
                float d = sx + sy; d = d + sz;
                float m = fminf(md[j], d);
                md[j] = m;
                bool c = m > bv;                 // strict >: first j wins ties
                bv = c ? m : bv;
                bx = c ? px[j] : bx;
                by = c ? py[j] : by;
                bz = c ? pz[j] : bz;
            }
            // wave max via DPP (result valid in lane 63), then SGPR broadcast
            float v = bv;
            DPP_MAX(v, 0x111);   // row_shr:1
            DPP_MAX(v, 0x112);   // row_shr:2
            DPP_MAX(v, 0x114);   // row_shr:4
            DPP_MAX(v, 0x118);   // row_shr:8
            DPP_MAX(v, 0x142);   // row_bcast:15
            DPP_MAX(v, 0x143);   // row_bcast:31
            const float mx = __int_as_float(
                __builtin_amdgcn_readlane(__float_as_int(v), 63));
            unsigned long long tie = __ballot(bv == mx);
            if (lane == __ffsll(tie) - 1)        // lowest lane among ties
                slot[par][wid] = make_float4(mx, bx, by, bz);
            __syncthreads();
            float4 s0 = slot[par][0], s1 = slot[par][1];
            float4 s2 = slot[par][2], s3 = slot[par][3];
            float4 s4 = slot[par][4], s5 = slot[par][5];
            float4 s6 = slot[par][6], s7 = slot[par][7];
            float4 a01 = (s1.x > s0.x) ? s1 : s0;   // ties keep lower wave
            float4 a23 = (s3.x > s2.x) ? s3 : s2;
            float4 a45 = (s5.x > s4.x) ? s5 : s4;
            float4 a67 = (s7.x > s6.x) ? s7 : s6;
            float4 b03 = (a23.x > a01.x) ? a23 : a01;
            float4 b47 = (a67.x > a45.x) ? a67 : a45;
            float4 wn = (b47.x > b03.x) ? b47 : b03;
            cx = wn.y; cy = wn.z; cz = wn.w;
            if (tid == 0) {
                size_t o = (size_t)(b * NS + t) * 3;
                centers[o + 0] = cx; centers[o + 1] = cy; centers[o + 2] = cz;
                out_pos[o + 0] = cx; out_pos[o + 1] = cy; out_pos[o + 2] = cz;
                if ((t & 15) == 15)   // cadence-16 publish; t=1023 -> 1024
                    __hip_atomic_store(&prog[b * PROGSTRIDE], (unsigned)(t + 1),
                                       __ATOMIC_RELEASE, __HIP_MEMORY_SCOPE_AGENT);
            }
            par ^= 1;
        }
    } else {
        // ---------------- consumers: weight prep, then select ----------------
        const int wblk = blockIdx.x - NB;        // 0..247
        // prep in the spin shadow (workers would idle until first publish)
        {
            const int wtid = wblk * 512 + tid;   // 0..126975
            const int NW = 248 * 512;
#pragma unroll 1
            for (int m = 0; m < 9; ++m) {
                const int kp = pa.kp[m], kr = pa.kr[m], nc = pa.nc[m];
                const float* src = pa.src[m];
                _Float16* dst = pa.dst[m];
                const int tot = kp * nc;
                for (int i = wtid; i < tot; i += NW) {
                    int n = i / kp, k = i - n * kp;
                    dst[i] = (k < kr) ? (_Float16)src[(size_t)k * nc + n]
                                      : (_Float16)0.f;
                }
            }
        }
        const int wid = tid >> 6;                // 0..7
        const int wave_id = wblk * 8 + wid;      // 0..1983
        const int NWAVE = 248 * 8;               // 1984
        const int NTASK = 3 * NB * NS;           // 24576
        for (int T = wave_id; T < NTASK; T += NWAVE) {
            const int s = T / 24;                // center index, ascending
            const int r = T - s * 24;
            const int b = r & 7;
            const int seg = r >> 3;
            const int scid = b * NS + s;
            while (__hip_atomic_load(&prog[b * PROGSTRIDE], __ATOMIC_ACQUIRE,
                                     __HIP_MEMORY_SCOPE_AGENT) <= (unsigned)s)
                __builtin_amdgcn_s_sleep(32);
            const float* pb = pos + (size_t)b * NP * 3;
            if (seg == 0)
                select_center<16>(pb, centers, nbr0, nval,
                                  (float)(0.1 * 0.1), scid);
            else if (seg == 1)
                select_center<32>(pb, centers, nbr1, nval + 8192,
                                  (float)(0.2 * 0.2), scid);
            else
                select_center<64>(pb, centers, nbr2, nval + 16384,
                                  (float)(0.4 * 0.4), scid);
        }
    }
}

// =========================== MFMA MLP ==============================
// ROUND-10 CHANGE: double-buffered gather. R9's counter evidence showed the
// per-center gather round-trip is exposed latency (1-block/CU mlp ran at
// ~31% wave-throughput; the co-resident 2nd block in mlp_all is what hides
// it). New schedule per center: gate barrier -> zero outmax -> ISSUE next
// center's gather into the other feat buffer -> L1 compute (covers the load
// latency; the L1-end barrier's vmcnt drain is then free) -> L2 -> L3 ->
// out-write. Buffers disjoint by parity; arithmetic unchanged.
// LDS (seg2): 2*13312(feat x2) + 17408(h1) + 17408(h2) + 1024(outmax)
// = 62464 B <= 64KB per-block cap; 2 blocks/CU = 124928 <= 160KB.
template <int M, int C1, int C2, int C3, int OFF, int NCTR>
__device__ void mlp_body(
        char* smem,
        const float* __restrict__ x, const float* __restrict__ pos,
        const float* __restrict__ centers,
        const int* __restrict__ nbr, const int* __restrict__ nvalid,
        const _Float16* __restrict__ wt1, const _Float16* __restrict__ wt2,
        const _Float16* __restrict__ wt3,
        const float* __restrict__ b1, const float* __restrict__ b2,
        const float* __restrict__ b3,
        float* __restrict__ out, int blk) {
    constexpr int K1P = 96;                 // 67 padded to 96
    constexpr int S1 = K1P + 8;             // 104 elems = 208 B
    constexpr int S2 = C1 + 8;
    constexpr int S3 = C2 + 8;
    constexpr int MT = M / 16;
    constexpr int NCH1 = C1 / 4, NCH2 = C2 / 4, NCH3 = C3 / 4;
    constexpr int NT1 = NCH1 / 16, NT2 = NCH2 / 16, NT3 = NCH3 / 16;
    constexpr int KT1 = K1P / 32, KT2 = C1 / 32, KT3 = C2 / 32;

    _Float16* feat0 = (_Float16*)smem;           // M*S1 each, 16B-aligned
    _Float16* feat1 = feat0 + M * S1;
    _Float16* h1 = feat1 + M * S1;
    _Float16* h2 = h1 + M * S2;
    int* outmax = (int*)(h2 + M * S3);           // C3 ints

    const int tid = threadIdx.x;
    const int lane = tid & 63;
    const int w = tid >> 6;
    const int lm = lane & 15;
    const int lq = lane >> 4;

    // ---- resident weight fragments + biases (per wave N-chunk) ----
    f16x8 wf1[NT1][KT1], wf2[NT2][KT2], wf3[NT3][KT3];
    float bb1[NT1], bb2[NT2], bb3[NT3];
#pragma unroll
    for (int nt = 0; nt < NT1; ++nt) {
        int n = w * NCH1 + nt * 16 + lm;
        bb1[nt] = b1[n];
#pragma unroll
        for (int kt = 0; kt < KT1; ++kt)
            wf1[nt][kt] = *(const f16x8*)(wt1 + (size_t)n * K1P + kt * 32 + lq * 8);
    }
#pragma unroll
    for (int nt = 0; nt < NT2; ++nt) {
        int n = w * NCH2 + nt * 16 + lm;
        bb2[nt] = b2[n];
#pragma unroll
        for (int kt = 0; kt < KT2; ++kt)
            wf2[nt][kt] = *(const f16x8*)(wt2 + (size_t)n * C1 + kt * 32 + lq * 8);
    }
#pragma unroll
    for (int nt = 0; nt < NT3; ++nt) {
        int n = w * NCH3 + nt * 16 + lm;
        bb3[nt] = b3[n];
#pragma unroll
        for (int kt = 0; kt < KT3; ++kt)
            wf3[nt][kt] = *(const f16x8*)(wt3 + (size_t)n * C2 + kt * 32 + lq * 8);
    }

    // gather one center's inputs into fb (x features + pos-rel + K-pad)
    auto gather = [&](int cid, _Float16* fb) {
        const int bidx = cid >> 10;
        const int nv = nvalid[cid];
        const float cx = centers[cid * 3 + 0];
        const float cy = centers[cid * 3 + 1];
        const float cz = centers[cid * 3 + 2];
        // pass A: x features, 16 lanes/row, float4 -> f16x4; stale rows are
        // row-local through MFMA, relu(NaN)=0, masked at layer 3.
        for (int it = tid; it < M * 16; it += 256) {
            const int r = it >> 4, sub = it & 15;
            if (r < nv) {
                int pt = nbr[(size_t)cid * M + r];
                float4 v = *(const float4*)(x + ((size_t)(bidx * NP) + pt) * 64 + sub * 4);
                f16x4 hv = {(_Float16)v.x, (_Float16)v.y, (_Float16)v.z, (_Float16)v.w};
                *(f16x4*)(fb + r * S1 + sub * 4) = hv;
            }
        }
        // pass B: pos-rel + zero K-pad (cols 64..95)
        for (int it = tid; it < M * 4; it += 256) {
            const int r = it >> 2, q = it & 3;
            f16x8 z = {(_Float16)0.f, (_Float16)0.f, (_Float16)0.f, (_Float16)0.f,
                       (_Float16)0.f, (_Float16)0.f, (_Float16)0.f, (_Float16)0.f};
            if (q == 0 && r < nv) {
                int pt = nbr[(size_t)cid * M + r];
                const float* pr = pos + ((size_t)(bidx * NP) + pt) * 3;
                z[0] = (_Float16)(pr[0] - cx);
                z[1] = (_Float16)(pr[1] - cy);
                z[2] = (_Float16)(pr[2] - cz);
            }
            *(f16x8*)(fb + r * S1 + 64 + q * 8) = z;
        }
    };

    gather(blk * NCTR, feat0);   // prologue (latency exposed once per block)

    for (int cc = 0; cc < NCTR; ++cc) {
        const int cid = blk * NCTR + cc;
        const int nv = nvalid[cid];
        _Float16* feat = (cc & 1) ? feat1 : feat0;
        __syncthreads();   // gate: feat[cc] complete; prev out-write done

        for (int i = tid; i < C3; i += 256) outmax[i] = 0;
        if (cc + 1 < NCTR)                     // prefetch next center; drains
            gather(cid + 1, (cc & 1) ? feat0 : feat1);  // at L1-end barrier

        // ---- layer 1: feat[M x 96] -> h1[M x C1] ----
#pragma unroll
        for (int mt = 0; mt < MT; ++mt) {
            f16x8 a[KT1];
#pragma unroll
            for (int kt = 0; kt < KT1; ++kt)
                a[kt] = *(const f16x8*)(feat + (mt * 16 + lm) * S1 + kt * 32 + lq * 8);
#pragma unroll
            for (int nt = 0; nt < NT1; ++nt) {
                f32x4 acc = {bb1[nt], bb1[nt], bb1[nt], bb1[nt]};
#pragma unroll
                for (int kt = 0; kt < KT1; ++kt)
                    acc = __builtin_amdgcn_mfma_f32_16x16x32_f16(a[kt], wf1[nt][kt], acc, 0, 0, 0);
                const int gc = w * NCH1 + nt * 16 + lm;
#pragma unroll
                for (int rg = 0; rg < 4; ++rg)
                    h1[(mt * 16 + lq * 4 + rg) * S2 + gc] = (_Float16)fmaxf(acc[rg], 0.f);
            }
        }
        __syncthreads();

        // ---- layer 2: h1[M x C1] -> h2[M x C2] ----
#pragma unroll
        for (int mt = 0; mt < MT; ++mt) {
            f16x8 a[KT2];
#pragma unroll
            for (int kt = 0; kt < KT2; ++kt)
                a[kt] = *(const f16x8*)(h1 + (mt * 16 + lm) * S2 + kt * 32 + lq * 8);
#pragma unroll
            for (int nt = 0; nt < NT2; ++nt) {
                f32x4 acc = {bb2[nt], bb2[nt], bb2[nt], bb2[nt]};
#pragma unroll
                for (int kt = 0; kt < KT2; ++kt)
                    acc = __builtin_amdgcn_mfma_f32_16x16x32_f16(a[kt], wf2[nt][kt], acc, 0, 0, 0);
                const int gc = w * NCH2 + nt * 16 + lm;
#pragma unroll
                for (int rg = 0; rg < 4; ++rg)
                    h2[(mt * 16 + lq * 4 + rg) * S3 + gc] = (_Float16)fmaxf(acc[rg], 0.f);
            }
        }
        __syncthreads();

        // ---- layer 3 + masked max ----
#pragma unroll
        for (int mt = 0; mt < MT; ++mt) {
            f16x8 a[KT3];
#pragma unroll
            for (int kt = 0; kt < KT3; ++kt)
                a[kt] = *(const f16x8*)(h2 + (mt * 16 + lm) * S3 + kt * 32 + lq * 8);
#pragma unroll
            for (int nt = 0; nt < NT3; ++nt) {
                f32x4 acc = {bb3[nt], bb3[nt], bb3[nt], bb3[nt]};
#pragma unroll
                for (int kt = 0; kt < KT3; ++kt)
                    acc = __builtin_amdgcn_mfma_f32_16x16x32_f16(a[kt], wf3[nt][kt], acc, 0, 0, 0);
                float mx = -1.f;
#pragma unroll
                for (int rg = 0; rg < 4; ++rg) {
                    int row = mt * 16 + lq * 4 + rg;
                    float v = fmaxf(acc[rg], 0.f);
                    if (row < nv) mx = fmaxf(mx, v);
                }
                mx = fmaxf(mx, __shfl_xor(mx, 16));
                mx = fmaxf(mx, __shfl_xor(mx, 32));
                if (lane < 16)
                    atomicMax(&outmax[w * NCH3 + nt * 16 + lm], __float_as_int(mx));
            }
        }
        __syncthreads();
        for (int i = tid; i < C3; i += 256)
            out[(size_t)cid * 640 + OFF + i] = __int_as_float(outmax[i]);
        // next iteration's gate barrier orders this against outmax re-zero
    }
}

struct MlpW {
    const _Float16* w[9];
    const float* bias[9];
};

__global__ __launch_bounds__(256, 2) void mlp_all(
        const float* __restrict__ x, const float* __restrict__ pos,
        const float* __restrict__ centers,
        const int* __restrict__ nbr0, const int* __restrict__ nbr1,
        const int* __restrict__ nbr2, const int* __restrict__ nval,
        MlpW ww, float* __restrict__ out) {
    extern __shared__ char smem[];
    const int blk = blockIdx.x;
    if (blk < 1024)
        mlp_body<16, 64, 64, 128, 0, 8>(smem, x, pos, centers, nbr0, nval,
            ww.w[0], ww.w[1], ww.w[2], ww.bias[0], ww.bias[1], ww.bias[2], out, blk);
    else if (blk < 2048)
        mlp_body<32, 128, 128, 256, 128, 8>(smem, x, pos, centers, nbr1, nval + 8192,
            ww.w[3], ww.w[4], ww.w[5], ww.bias[3], ww.bias[4], ww.bias[5], out, blk - 1024);
    else
        mlp_body<64, 128, 128, 256, 384, 8>(smem, x, pos, centers, nbr2, nval + 16384,
            ww.w[6], ww.w[7], ww.w[8], ww.bias[6], ww.bias[7], ww.bias[8], out, blk - 2048);
}

// ========================= launcher ===========================
extern "C" void kernel_launch(void* const* d_in, const int* in_sizes, int n_in,
                              void* d_out, int out_size, void* d_ws, size_t ws_size,
                              hipStream_t stream) {
    const float* x = (const float*)d_in[0];
    const float* pos = (const float*)d_in[1];
    const float* W0_0 = (const float*)d_in[3];
    const float* b0_0 = (const float*)d_in[4];
    const float* W0_1 = (const float*)d_in[5];
    const float* b0_1 = (const float*)d_in[6];
    const float* W0_2 = (const float*)d_in[7];
    const float* b0_2 = (const float*)d_in[8];
    const float* W1_0 = (const float*)d_in[9];
    const float* b1_0 = (const float*)d_in[10];
    const float* W1_1 = (const float*)d_in[11];
    const float* b1_1 = (const float*)d_in[12];
    const float* W1_2 = (const float*)d_in[13];
    const float* b1_2 = (const float*)d_in[14];
    const float* W2_0 = (const float*)d_in[15];
    const float* b2_0 = (const float*)d_in[16];
    const float* W2_1 = (const float*)d_in[17];
    const float* b2_1 = (const float*)d_in[18];
    const float* W2_2 = (const float*)d_in[19];
    const float* b2_2 = (const float*)d_in[20];

    float* out = (float*)d_out;
    char* ws = (char*)d_ws;
    float* centers = (float*)(ws + 0);                 //  98304 B
    int* nbr0 = (int*)(ws + 98304);                    //  524288 B
    int* nbr1 = (int*)(ws + 622592);                   //  1048576 B
    int* nbr2 = (int*)(ws + 1671168);                  //  2097152 B
    int* nval = (int*)(ws + 3768320);                  //  98304 B
    // f16 transposed weights
    _Float16* w0t1 = (_Float16*)(ws + 3866624);        //  64*96  = 12288 B
    _Float16* w0t2 = (_Float16*)(ws + 3878912);        //  64*64  =  8192 B
    _Float16* w0t3 = (_Float16*)(ws + 3887104);        // 128*64  = 16384 B
    _Float16* w1t1 = (_Float16*)(ws + 3903488);        // 128*96  = 24576 B
    _Float16* w1t2 = (_Float16*)(ws + 3928064);        // 128*128 = 32768 B
    _Float16* w1t3 = (_Float16*)(ws + 3960832);        // 256*128 = 65536 B
    _Float16* w2t1 = (_Float16*)(ws + 4026368);
    _Float16* w2t2 = (_Float16*)(ws + 4050944);
    _Float16* w2t3 = (_Float16*)(ws + 4083712);        // end 4149248 B
    unsigned* prog = (unsigned*)(ws + 4149248);        // 8 x 128B progress lines

    float* out_pos = out + (size_t)8192 * 640;
    float* out_batch = out_pos + (size_t)8192 * 3;

    hipMemsetAsync(prog, 0, NB * PROGSTRIDE * sizeof(unsigned), stream);

    PrepArgs pa;
    pa.src[0] = W0_0; pa.dst[0] = w0t1; pa.kr[0] = 67;  pa.kp[0] = 96;  pa.nc[0] = 64;
    pa.src[1] = W0_1; pa.dst[1] = w0t2; pa.kr[1] = 64;  pa.kp[1] = 64;  pa.nc[1] = 64;
    pa.src[2] = W0_2; pa.dst[2] = w0t3; pa.kr[2] = 64;  pa.kp[2] = 64;  pa.nc[2] = 128;
    pa.src[3] = W1_0; pa.dst[3] = w1t1; pa.kr[3] = 67;  pa.kp[3] = 96;  pa.nc[3] = 128;
    pa.src[4] = W1_1; pa.dst[4] = w1t2; pa.kr[4] = 128; pa.kp[4] = 128; pa.nc[4] = 128;
    pa.src[5] = W1_2; pa.dst[5] = w1t3; pa.kr[5] = 128; pa.kp[5] = 128; pa.nc[5] = 256;
    pa.src[6] = W2_0; pa.dst[6] = w2t1; pa.kr[6] = 67;  pa.kp[6] = 96;  pa.nc[6] = 128;
    pa.src[7] = W2_1; pa.dst[7] = w2t2; pa.kr[7] = 128; pa.kp[7] = 128; pa.nc[7] = 128;
    pa.src[8] = W2_2; pa.dst[8] = w2t3; pa.kr[8] = 128; pa.kp[8] = 128; pa.nc[8] = 256;

    fps_select_fused<<<dim3(256), dim3(512), 0, stream>>>(
        pos, centers, out_pos, out_batch, nbr0, nbr1, nbr2, nval, prog, pa);

    MlpW ww;
    ww.w[0] = w0t1; ww.w[1] = w0t2; ww.w[2] = w0t3;
    ww.w[3] = w1t1; ww.w[4] = w1t2; ww.w[5] = w1t3;
    ww.w[6] = w2t1; ww.w[7] = w2t2; ww.w[8] = w2t3;
    ww.bias[0] = b0_0; ww.bias[1] = b0_1; ww.bias[2] = b0_2;
    ww.bias[3] = b1_0; ww.bias[4] = b1_1; ww.bias[5] = b1_2;
    ww.bias[6] = b2_0; ww.bias[7] = b2_1; ww.bias[8] = b2_2;

    // dynamic LDS = scale-2 dbuf footprint:
    // 2*(64*104*2) + 64*136*2 + 64*136*2 + 256*4 = 62464 B
    mlp_all<<<dim3(3072), dim3(256), 62464, stream>>>(
        x, pos, centers, nbr0, nbr1, nbr2, nval, ww, out);
}

// Round 11
// 1100.961 us; speedup vs baseline: 5.6548x; 1.0132x over previous
//
#include <hip/hip_runtime.h>

#define NB 8
#define NP 4096
#define NS 1024
#define PROGSTRIDE 32   // one 128B cache line per cloud's progress word

typedef _Float16 f16x8 __attribute__((ext_vector_type(8)));
typedef _Float16 f16x4 __attribute__((ext_vector_type(4)));
typedef float f32x4 __attribute__((ext_vector_type(4)));

// DPP-fused max step: v = max(v, dpp_move(v, ctrl)). bound_ctrl=false keeps
// old value on invalid lanes -> max(v,v)=v, harmless.
#define DPP_MAX(v, ctrl)                                                     \
    v = fmaxf(v, __int_as_float(__builtin_amdgcn_update_dpp(                 \
                __float_as_int(v), __float_as_int(v), (ctrl), 0xf, 0xf, false)))

struct PrepArgs {
    const float* src[9];
    _Float16* dst[9];
    int kr[9], kp[9], nc[9];
};

// ========================= Selection body ==========================
// Early-exit binary search on uint(d2) bits, no LDS staging, one center per
// wave. Bit-identical to exact top-k (tie path kept as fallback). FROZEN.
template <int K>
__device__ __forceinline__ void select_center(
        const float* __restrict__ pb,
        const float* __restrict__ centers,
        int* __restrict__ nbr, int* __restrict__ nvalid,
        float r2, int scid) {
#pragma clang fp contract(off)
    const int lane = threadIdx.x & 63;
    const unsigned kr2 = __float_as_uint(r2);
    const float cx = centers[scid * 3 + 0];
    const float cy = centers[scid * 3 + 1];
    const float cz = centers[scid * 3 + 2];

    unsigned key[64];
#pragma unroll
    for (int i = 0; i < 64; ++i) {
        const float* pp = pb + (size_t)(lane + i * 64) * 3;
        float dx = pp[0] - cx; float sx = dx * dx;
        float dy = pp[1] - cy; float sy = dy * dy;
        float dz = pp[2] - cz; float sz = dz * dz;
        float d2 = sx + sy; d2 = d2 + sz;
        key[i] = __float_as_uint(d2);
    }

    const unsigned long long below = (1ull << lane) - 1ull;
    int c_cnt = 0;
#pragma unroll
    for (int i = 0; i < 64; ++i)
        c_cnt += __popcll(__ballot(key[i] <= kr2));

    unsigned thr = kr2;          // threshold for the no-ties write pass
    int nv = c_cnt;
    bool need_ties = false;
    unsigned tkey = 0;
    if (c_cnt > K) {
        nv = K;
        unsigned lo = 0, hi = kr2;
        need_ties = true;
        while (lo < hi) {
            unsigned mid = lo + ((hi - lo) >> 1);
            int cnt = 0;
#pragma unroll
            for (int i = 0; i < 64; ++i)
                cnt += __popcll(__ballot(key[i] <= mid));
            if (cnt == K) { thr = mid; need_ties = false; break; }
            if (cnt > K) hi = mid; else lo = mid + 1;
        }
        tkey = lo;               // only meaningful if need_ties
    }

    if (!need_ties) {
        int base = 0;
#pragma unroll
        for (int i = 0; i < 64; ++i) {
            unsigned long long m = __ballot(key[i] <= thr);
            if (key[i] <= thr)
                nbr[(size_t)scid * K + base + __popcll(m & below)] = lane + i * 64;
            base += __popcll(m);
        }
    } else {
        const unsigned t = tkey;
        int m_cnt = 0;
#pragma unroll
        for (int i = 0; i < 64; ++i)
            m_cnt += __popcll(__ballot(key[i] < t));
        const int rem = K - m_cnt;
        int base = 0, tcnt = 0;
#pragma unroll
        for (int i = 0; i < 64; ++i) {
            unsigned long long lt = __ballot(key[i] < t);
            unsigned long long eq = __ballot(key[i] == t);
            if (key[i] < t) {
                nbr[(size_t)scid * K + base + __popcll(lt & below)] = lane + i * 64;
            } else if (key[i] == t) {
                int tr = tcnt + __popcll(eq & below);
                if (tr < rem) nbr[(size_t)scid * K + (m_cnt + tr)] = lane + i * 64;
            }
            base += __popcll(lt);
            tcnt += __popcll(eq);
        }
    }
    if (lane == 0) nvalid[scid] = nv;
}

// ================== FUSED FPS (producers) + SELECT (consumers) ==============
// MEASURED-GOOD (fused dispatch ~801us, twice-stable). fps 8 blocks + 248
// select worker blocks (1984 waves), prep in worker preamble, padded prog
// lines, s_sleep(32), cadence-16 publish. FROZEN — R3 (LDS cbuf), R5 (spin
// contention), R7/R9 (triple fusion) all measured neutral or worse.
__global__ __launch_bounds__(512, 1) void fps_select_fused(
        const float* __restrict__ pos,
        float* __restrict__ centers,
        float* __restrict__ out_pos,
        float* __restrict__ out_batch,
        int* __restrict__ nbr0, int* __restrict__ nbr1, int* __restrict__ nbr2,
        int* __restrict__ nval,
        unsigned* __restrict__ prog,
        PrepArgs pa) {
#pragma clang fp contract(off)
    const int tid = threadIdx.x;
    const int lane = tid & 63;

    if (blockIdx.x < NB) {
        // ------------------------ producer: FPS ------------------------
        const int b = blockIdx.x;
        const int wid = tid >> 6;
        __shared__ float4 slot[2][8];   // [parity][wave]

        const float* pb = pos + (size_t)b * NP * 3;
        float px[8], py[8], pz[8], md[8];
        {
            const float4* pv = (const float4*)(pb + tid * 24);
            float4 q0 = pv[0], q1 = pv[1], q2 = pv[2];
            float4 q3 = pv[3], q4 = pv[4], q5 = pv[5];
            px[0] = q0.x; py[0] = q0.y; pz[0] = q0.z;
            px[1] = q0.w; py[1] = q1.x; pz[1] = q1.y;
            px[2] = q1.z; py[2] = q1.w; pz[2] = q2.x;
            px[3] = q2.y; py[3] = q2.z; pz[3] = q2.w;
            px[4] = q3.x; py[4] = q3.y; pz[4] = q3.z;
            px[5] = q3.w; py[5] = q4.x; pz[5] = q4.y;
            px[6] = q4.z; py[6] = q4.w; pz[6] = q5.x;
            px[7] = q5.y; py[7] = q5.z; pz[7] = q5.w;
        }
#pragma unroll
        for (int j = 0; j < 8; ++j) md[j] = __builtin_inff();
        for (int t = tid; t < NS; t += 512) out_batch[b * NS + t] = (float)b;

        float cx = pb[0], cy = pb[1], cz = pb[2];
        if (tid == 0) {
            size_t o = (size_t)(b * NS) * 3;
            centers[o + 0] = cx; centers[o + 1] = cy; centers[o + 2] = cz;
            out_pos[o + 0] = cx; out_pos[o + 1] = cy; out_pos[o + 2] = cz;
        }

        int par = 0;
        for (int t = 1; t < NS; ++t) {
            float bv = -1.0f, bx = cx, by = cy, bz = cz;
#pragma unroll
            for (int j = 0; j < 8; ++j) {
                float dx = px[j] - cx; float sx = dx * dx;
                float dy = py[j] - cy; float sy = dy * dy;
                float dz = pz[j] - cz; float sz = dz * dz;
                float d = sx + sy; d = d + sz;
                float m = fminf(md[j], d);
                md[j] = m;
                bool c = m > bv;                 // strict >: first j wins ties
                bv = c ? m : bv;
                bx = c ? px[j] : bx;
                by = c ? py[j] : by;
                bz = c ? pz[j] : bz;
            }
            // wave max via DPP (result valid in lane 63), then SGPR broadcast
            float v = bv;
            DPP_MAX(v, 0x111);   // row_shr:1
            DPP_MAX(v, 0x112);   // row_shr:2
            DPP_MAX(v, 0x114);   // row_shr:4
            DPP_MAX(v, 0x118);   // row_shr:8
            DPP_MAX(v, 0x142);   // row_bcast:15
            DPP_MAX(v, 0x143);   // row_bcast:31
            const float mx = __int_as_float(
                __builtin_amdgcn_readlane(__float_as_int(v), 63));
            unsigned long long tie = __ballot(bv == mx);
            if (lane == __ffsll(tie) - 1)        // lowest lane among ties
                slot[par][wid] = make_float4(mx, bx, by, bz);
            __syncthreads();
            float4 s0 = slot[par][0], s1 = slot[par][1];
            float4 s2 = slot[par][2], s3 = slot[par][3];
            float4 s4 = slot[par][4], s5 = slot[par][5];
            float4 s6 = slot[par][6], s7 = slot[par][7];
            float4 a01 = (s1.x > s0.x) ? s1 : s0;   // ties keep lower wave
            float4 a23 = (s3.x > s2.x) ? s3 : s2;
            float4 a45 = (s5.x > s4.x) ? s5 : s4;
            float4 a67 = (s7.x > s6.x) ? s7 : s6;
            float4 b03 = (a23.x > a01.x) ? a23 : a01;
            float4 b47 = (a67.x > a45.x) ? a67 : a45;
            float4 wn = (b47.x > b03.x) ? b47 : b03;
            cx = wn.y; cy = wn.z; cz = wn.w;
            if (tid == 0) {
                size_t o = (size_t)(b * NS + t) * 3;
                centers[o + 0] = cx; centers[o + 1] = cy; centers[o + 2] = cz;
                out_pos[o + 0] = cx; out_pos[o + 1] = cy; out_pos[o + 2] = cz;
                if ((t & 15) == 15)   // cadence-16 publish; t=1023 -> 1024
                    __hip_atomic_store(&prog[b * PROGSTRIDE], (unsigned)(t + 1),
                                       __ATOMIC_RELEASE, __HIP_MEMORY_SCOPE_AGENT);
            }
            par ^= 1;
        }
    } else {
        // ---------------- consumers: weight prep, then select ----------------
        const int wblk = blockIdx.x - NB;        // 0..247
        // prep in the spin shadow (workers would idle until first publish)
        {
            const int wtid = wblk * 512 + tid;   // 0..126975
            const int NW = 248 * 512;
#pragma unroll 1
            for (int m = 0; m < 9; ++m) {
                const int kp = pa.kp[m], kr = pa.kr[m], nc = pa.nc[m];
                const float* src = pa.src[m];
                _Float16* dst = pa.dst[m];
                const int tot = kp * nc;
                for (int i = wtid; i < tot; i += NW) {
                    int n = i / kp, k = i - n * kp;
                    dst[i] = (k < kr) ? (_Float16)src[(size_t)k * nc + n]
                                      : (_Float16)0.f;
                }
            }
        }
        const int wid = tid >> 6;                // 0..7
        const int wave_id = wblk * 8 + wid;      // 0..1983
        const int NWAVE = 248 * 8;               // 1984
        const int NTASK = 3 * NB * NS;           // 24576
        for (int T = wave_id; T < NTASK; T += NWAVE) {
            const int s = T / 24;                // center index, ascending
            const int r = T - s * 24;
            const int b = r & 7;
            const int seg = r >> 3;
            const int scid = b * NS + s;
            while (__hip_atomic_load(&prog[b * PROGSTRIDE], __ATOMIC_ACQUIRE,
                                     __HIP_MEMORY_SCOPE_AGENT) <= (unsigned)s)
                __builtin_amdgcn_s_sleep(32);
            const float* pb = pos + (size_t)b * NP * 3;
            if (seg == 0)
                select_center<16>(pb, centers, nbr0, nval,
                                  (float)(0.1 * 0.1), scid);
            else if (seg == 1)
                select_center<32>(pb, centers, nbr1, nval + 8192,
                                  (float)(0.2 * 0.2), scid);
            else
                select_center<64>(pb, centers, nbr2, nval + 16384,
                                  (float)(0.4 * 0.4), scid);
        }
    }
}

// =========================== MFMA MLP ==============================
// R10's double-buffered gather retained (measured neutral, not harmful; 4
// barriers/center). ROUND-11 CHANGE is in mlp_all's block->center mapping
// (cloud->XCD affinity), not here.
template <int M, int C1, int C2, int C3, int OFF, int NCTR>
__device__ void mlp_body(
        char* smem,
        const float* __restrict__ x, const float* __restrict__ pos,
        const float* __restrict__ centers,
        const int* __restrict__ nbr, const int* __restrict__ nvalid,
        const _Float16* __restrict__ wt1, const _Float16* __restrict__ wt2,
        const _Float16* __restrict__ wt3,
        const float* __restrict__ b1, const float* __restrict__ b2,
        const float* __restrict__ b3,
        float* __restrict__ out, int blk) {
    constexpr int K1P = 96;                 // 67 padded to 96
    constexpr int S1 = K1P + 8;             // 104 elems = 208 B
    constexpr int S2 = C1 + 8;
    constexpr int S3 = C2 + 8;
    constexpr int MT = M / 16;
    constexpr int NCH1 = C1 / 4, NCH2 = C2 / 4, NCH3 = C3 / 4;
    constexpr int NT1 = NCH1 / 16, NT2 = NCH2 / 16, NT3 = NCH3 / 16;
    constexpr int KT1 = K1P / 32, KT2 = C1 / 32, KT3 = C2 / 32;

    _Float16* feat0 = (_Float16*)smem;           // M*S1 each, 16B-aligned
    _Float16* feat1 = feat0 + M * S1;
    _Float16* h1 = feat1 + M * S1;
    _Float16* h2 = h1 + M * S2;
    int* outmax = (int*)(h2 + M * S3);           // C3 ints

    const int tid = threadIdx.x;
    const int lane = tid & 63;
    const int w = tid >> 6;
    const int lm = lane & 15;
    const int lq = lane >> 4;

    // ---- resident weight fragments + biases (per wave N-chunk) ----
    f16x8 wf1[NT1][KT1], wf2[NT2][KT2], wf3[NT3][KT3];
    float bb1[NT1], bb2[NT2], bb3[NT3];
#pragma unroll
    for (int nt = 0; nt < NT1; ++nt) {
        int n = w * NCH1 + nt * 16 + lm;
        bb1[nt] = b1[n];
#pragma unroll
        for (int kt = 0; kt < KT1; ++kt)
            wf1[nt][kt] = *(const f16x8*)(wt1 + (size_t)n * K1P + kt * 32 + lq * 8);
    }
#pragma unroll
    for (int nt = 0; nt < NT2; ++nt) {
        int n = w * NCH2 + nt * 16 + lm;
        bb2[nt] = b2[n];
#pragma unroll
        for (int kt = 0; kt < KT2; ++kt)
            wf2[nt][kt] = *(const f16x8*)(wt2 + (size_t)n * C1 + kt * 32 + lq * 8);
    }
#pragma unroll
    for (int nt = 0; nt < NT3; ++nt) {
        int n = w * NCH3 + nt * 16 + lm;
        bb3[nt] = b3[n];
#pragma unroll
        for (int kt = 0; kt < KT3; ++kt)
            wf3[nt][kt] = *(const f16x8*)(wt3 + (size_t)n * C2 + kt * 32 + lq * 8);
    }

    // gather one center's inputs into fb (x features + pos-rel + K-pad)
    auto gather = [&](int cid, _Float16* fb) {
        const int bidx = cid >> 10;
        const int nv = nvalid[cid];
        const float cx = centers[cid * 3 + 0];
        const float cy = centers[cid * 3 + 1];
        const float cz = centers[cid * 3 + 2];
        // pass A: x features, 16 lanes/row, float4 -> f16x4; stale rows are
        // row-local through MFMA, relu(NaN)=0, masked at layer 3.
        for (int it = tid; it < M * 16; it += 256) {
            const int r = it >> 4, sub = it & 15;
            if (r < nv) {
                int pt = nbr[(size_t)cid * M + r];
                float4 v = *(const float4*)(x + ((size_t)(bidx * NP) + pt) * 64 + sub * 4);
                f16x4 hv = {(_Float16)v.x, (_Float16)v.y, (_Float16)v.z, (_Float16)v.w};
                *(f16x4*)(fb + r * S1 + sub * 4) = hv;
            }
        }
        // pass B: pos-rel + zero K-pad (cols 64..95)
        for (int it = tid; it < M * 4; it += 256) {
            const int r = it >> 2, q = it & 3;
            f16x8 z = {(_Float16)0.f, (_Float16)0.f, (_Float16)0.f, (_Float16)0.f,
                       (_Float16)0.f, (_Float16)0.f, (_Float16)0.f, (_Float16)0.f};
            if (q == 0 && r < nv) {
                int pt = nbr[(size_t)cid * M + r];
                const float* pr = pos + ((size_t)(bidx * NP) + pt) * 3;
                z[0] = (_Float16)(pr[0] - cx);
                z[1] = (_Float16)(pr[1] - cy);
                z[2] = (_Float16)(pr[2] - cz);
            }
            *(f16x8*)(fb + r * S1 + 64 + q * 8) = z;
        }
    };

    gather(blk * NCTR, feat0);   // prologue (latency exposed once per block)

    for (int cc = 0; cc < NCTR; ++cc) {
        const int cid = blk * NCTR + cc;
        const int nv = nvalid[cid];
        _Float16* feat = (cc & 1) ? feat1 : feat0;
        __syncthreads();   // gate: feat[cc] complete; prev out-write done

        for (int i = tid; i < C3; i += 256) outmax[i] = 0;
        if (cc + 1 < NCTR)                     // prefetch next center; drains
            gather(cid + 1, (cc & 1) ? feat0 : feat1);  // at L1-end barrier

        // ---- layer 1: feat[M x 96] -> h1[M x C1] ----
#pragma unroll
        for (int mt = 0; mt < MT; ++mt) {
            f16x8 a[KT1];
#pragma unroll
            for (int kt = 0; kt < KT1; ++kt)
                a[kt] = *(const f16x8*)(feat + (mt * 16 + lm) * S1 + kt * 32 + lq * 8);
#pragma unroll
            for (int nt = 0; nt < NT1; ++nt) {
                f32x4 acc = {bb1[nt], bb1[nt], bb1[nt], bb1[nt]};
#pragma unroll
                for (int kt = 0; kt < KT1; ++kt)
                    acc = __builtin_amdgcn_mfma_f32_16x16x32_f16(a[kt], wf1[nt][kt], acc, 0, 0, 0);
                const int gc = w * NCH1 + nt * 16 + lm;
#pragma unroll
                for (int rg = 0; rg < 4; ++rg)
                    h1[(mt * 16 + lq * 4 + rg) * S2 + gc] = (_Float16)fmaxf(acc[rg], 0.f);
            }
        }
        __syncthreads();

        // ---- layer 2: h1[M x C1] -> h2[M x C2] ----
#pragma unroll
        for (int mt = 0; mt < MT; ++mt) {
            f16x8 a[KT2];
#pragma unroll
            for (int kt = 0; kt < KT2; ++kt)
                a[kt] = *(const f16x8*)(h1 + (mt * 16 + lm) * S2 + kt * 32 + lq * 8);
#pragma unroll
            for (int nt = 0; nt < NT2; ++nt) {
                f32x4 acc = {bb2[nt], bb2[nt], bb2[nt], bb2[nt]};
#pragma unroll
                for (int kt = 0; kt < KT2; ++kt)
                    acc = __builtin_amdgcn_mfma_f32_16x16x32_f16(a[kt], wf2[nt][kt], acc, 0, 0, 0);
                const int gc = w * NCH2 + nt * 16 + lm;
#pragma unroll
                for (int rg = 0; rg < 4; ++rg)
                    h2[(mt * 16 + lq * 4 + rg) * S3 + gc] = (_Float16)fmaxf(acc[rg], 0.f);
            }
        }
        __syncthreads();

        // ---- layer 3 + masked max ----
#pragma unroll
        for (int mt = 0; mt < MT; ++mt) {
            f16x8 a[KT3];
#pragma unroll
            for (int kt = 0; kt < KT3; ++kt)
                a[kt] = *(const f16x8*)(h2 + (mt * 16 + lm) * S3 + kt * 32 + lq * 8);
#pragma unroll
            for (int nt = 0; nt < NT3; ++nt) {
                f32x4 acc = {bb3[nt], bb3[nt], bb3[nt], bb3[nt]};
#pragma unroll
                for (int kt = 0; kt < KT3; ++kt)
                    acc = __builtin_amdgcn_mfma_f32_16x16x32_f16(a[kt], wf3[nt][kt], acc, 0, 0, 0);
                float mx = -1.f;
#pragma unroll
                for (int rg = 0; rg < 4; ++rg) {
                    int row = mt * 16 + lq * 4 + rg;
                    float v = fmaxf(acc[rg], 0.f);
                    if (row < nv) mx = fmaxf(mx, v);
                }
                mx = fmaxf(mx, __shfl_xor(mx, 16));
                mx = fmaxf(mx, __shfl_xor(mx, 32));
                if (lane < 16)
                    atomicMax(&outmax[w * NCH3 + nt * 16 + lm], __float_as_int(mx));
            }
        }
        __syncthreads();
        for (int i = tid; i < C3; i += 256)
            out[(size_t)cid * 640 + OFF + i] = __int_as_float(outmax[i]);
        // next iteration's gate barrier orders this against outmax re-zero
    }
}

struct MlpW {
    const _Float16* w[9];
    const float* bias[9];
};

// ROUND-11: cloud->XCD affinity remap. Old mapping: consecutive blocks =
// consecutive centers of the SAME cloud, dispatched round-robin over XCDs ->
// every XCD gathers from all 8 clouds (8MB x through each 4MB L2 = thrash).
// New mapping (bijective): cloud = sblk&7, octet = sblk>>3 -> with dispatch
// XCD ~ blk%8, each XCD works exactly one cloud per segment phase; its L2
// holds that cloud's 1MB x slab + 122KB weights -> gathers become L2 hits.
// Worst case (XCD mapping assumption wrong): perf-neutral permutation.
__global__ __launch_bounds__(256, 2) void mlp_all(
        const float* __restrict__ x, const float* __restrict__ pos,
        const float* __restrict__ centers,
        const int* __restrict__ nbr0, const int* __restrict__ nbr1,
        const int* __restrict__ nbr2, const int* __restrict__ nval,
        MlpW ww, float* __restrict__ out) {
    extern __shared__ char smem[];
    const int blk = blockIdx.x;
    const int sblk = blk & 1023;
    const int eblk = (sblk & 7) * 128 + (sblk >> 3);   // cloud*128 + octet
    if (blk < 1024)
        mlp_body<16, 64, 64, 128, 0, 8>(smem, x, pos, centers, nbr0, nval,
            ww.w[0], ww.w[1], ww.w[2], ww.bias[0], ww.bias[1], ww.bias[2], out, eblk);
    else if (blk < 2048)
        mlp_body<32, 128, 128, 256, 128, 8>(smem, x, pos, centers, nbr1, nval + 8192,
            ww.w[3], ww.w[4], ww.w[5], ww.bias[3], ww.bias[4], ww.bias[5], out, eblk);
    else
        mlp_body<64, 128, 128, 256, 384, 8>(smem, x, pos, centers, nbr2, nval + 16384,
            ww.w[6], ww.w[7], ww.w[8], ww.bias[6], ww.bias[7], ww.bias[8], out, eblk);
}

// ========================= launcher ===========================
extern "C" void kernel_launch(void* const* d_in, const int* in_sizes, int n_in,
                              void* d_out, int out_size, void* d_ws, size_t ws_size,
                              hipStream_t stream) {
    const float* x = (const float*)d_in[0];
    const float* pos = (const float*)d_in[1];
    const float* W0_0 = (const float*)d_in[3];
    const float* b0_0 = (const float*)d_in[4];
    const float* W0_1 = (const float*)d_in[5];
    const float* b0_1 = (const float*)d_in[6];
    const float* W0_2 = (const float*)d_in[7];
    const float* b0_2 = (const float*)d_in[8];
    const float* W1_0 = (const float*)d_in[9];
    const float* b1_0 = (const float*)d_in[10];
    const float* W1_1 = (const float*)d_in[11];
    const float* b1_1 = (const float*)d_in[12];
    const float* W1_2 = (const float*)d_in[13];
    const float* b1_2 = (const float*)d_in[14];
    const float* W2_0 = (const float*)d_in[15];
    const float* b2_0 = (const float*)d_in[16];
    const float* W2_1 = (const float*)d_in[17];
    const float* b2_1 = (const float*)d_in[18];
    const float* W2_2 = (const float*)d_in[19];
    const float* b2_2 = (const float*)d_in[20];

    float* out = (float*)d_out;
    char* ws = (char*)d_ws;
    float* centers = (float*)(ws + 0);                 //  98304 B
    int* nbr0 = (int*)(ws + 98304);                    //  524288 B
    int* nbr1 = (int*)(ws + 622592);                   //  1048576 B
    int* nbr2 = (int*)(ws + 1671168);                  //  2097152 B
    int* nval = (int*)(ws + 3768320);                  //  98304 B
    // f16 transposed weights
    _Float16* w0t1 = (_Float16*)(ws + 3866624);        //  64*96  = 12288 B
    _Float16* w0t2 = (_Float16*)(ws + 3878912);        //  64*64  =  8192 B
    _Float16* w0t3 = (_Float16*)(ws + 3887104);        // 128*64  = 16384 B
    _Float16* w1t1 = (_Float16*)(ws + 3903488);        // 128*96  = 24576 B
    _Float16* w1t2 = (_Float16*)(ws + 3928064);        // 128*128 = 32768 B
    _Float16* w1t3 = (_Float16*)(ws + 3960832);        // 256*128 = 65536 B
    _Float16* w2t1 = (_Float16*)(ws + 4026368);
    _Float16* w2t2 = (_Float16*)(ws + 4050944);
    _Float16* w2t3 = (_Float16*)(ws + 4083712);        // end 4149248 B
    unsigned* prog = (unsigned*)(ws + 4149248);        // 8 x 128B progress lines

    float* out_pos = out + (size_t)8192 * 640;
    float* out_batch = out_pos + (size_t)8192 * 3;

    hipMemsetAsync(prog, 0, NB * PROGSTRIDE * sizeof(unsigned), stream);

    PrepArgs pa;
    pa.src[0] = W0_0; pa.dst[0] = w0t1; pa.kr[0] = 67;  pa.kp[0] = 96;  pa.nc[0] = 64;
    pa.src[1] = W0_1; pa.dst[1] = w0t2; pa.kr[1] = 64;  pa.kp[1] = 64;  pa.nc[1] = 64;
    pa.src[2] = W0_2; pa.dst[2] = w0t3; pa.kr[2] = 64;  pa.kp[2] = 64;  pa.nc[2] = 128;
    pa.src[3] = W1_0; pa.dst[3] = w1t1; pa.kr[3] = 67;  pa.kp[3] = 96;  pa.nc[3] = 128;
    pa.src[4] = W1_1; pa.dst[4] = w1t2; pa.kr[4] = 128; pa.kp[4] = 128; pa.nc[4] = 128;
    pa.src[5] = W1_2; pa.dst[5] = w1t3; pa.kr[5] = 128; pa.kp[5] = 128; pa.nc[5] = 256;
    pa.src[6] = W2_0; pa.dst[6] = w2t1; pa.kr[6] = 67;  pa.kp[6] = 96;  pa.nc[6] = 128;
    pa.src[7] = W2_1; pa.dst[7] = w2t2; pa.kr[7] = 128; pa.kp[7] = 128; pa.nc[7] = 128;
    pa.src[8] = W2_2; pa.dst[8] = w2t3; pa.kr[8] = 128; pa.kp[8] = 128; pa.nc[8] = 256;

    fps_select_fused<<<dim3(256), dim3(512), 0, stream>>>(
        pos, centers, out_pos, out_batch, nbr0, nbr1, nbr2, nval, prog, pa);

    MlpW ww;
    ww.w[0] = w0t1; ww.w[1] = w0t2; ww.w[2] = w0t3;
    ww.w[3] = w1t1; ww.w[4] = w1t2; ww.w[5] = w1t3;
    ww.w[6] = w2t1; ww.w[7] = w2t2; ww.w[8] = w2t3;
    ww.bias[0] = b0_0; ww.bias[1] = b0_1; ww.bias[2] = b0_2;
    ww.bias[3] = b1_0; ww.bias[4] = b1_1; ww.bias[5] = b1_2;
    ww.bias[6] = b2_0; ww.bias[7] = b2_1; ww.bias[8] = b2_2;

    // dynamic LDS = scale-2 dbuf footprint:
    // 2*(64*104*2) + 64*136*2 + 64*136*2 + 256*4 = 62464 B
    mlp_all<<<dim3(3072), dim3(256), 62464, stream>>>(
        x, pos, centers, nbr0, nbr1, nbr2, nval, ww, out);
}